// Round 9
// baseline (462.991 us; speedup 1.0000x reference)
//
#include <hip/hip_runtime.h>
#include <hip/hip_bf16.h>
#include <math.h>

#define FEAT 96
#define ACTF 32

using frag8 = __attribute__((ext_vector_type(8))) short;   // 8 bf16 (4 VGPRs)
using f32x4 = __attribute__((ext_vector_type(4))) float;

__device__ __forceinline__ float lrelu(float x) { return x >= 0.f ? x : 0.2f * x; }
__device__ __forceinline__ void atomAddF(float* p, float v) {
    __hip_atomic_fetch_add(p, v, __ATOMIC_RELAXED, __HIP_MEMORY_SCOPE_AGENT);
}
__device__ __forceinline__ float expc(float x) { return __expf(fminf(x, 60.f)); }
__device__ __forceinline__ unsigned short f2bf(float f) {
    __hip_bfloat16 h = __float2bfloat16(f);
    return *(unsigned short*)&h;
}

// ---------- embedding: x0[N,64] = [nf|act] @ Wemb[128,64] + bemb ----------
__global__ __launch_bounds__(256) void emb_kernel(
    const float* __restrict__ nf, const float* __restrict__ act,
    const float* __restrict__ Wemb, const float* __restrict__ bemb,
    float* __restrict__ x0, int N) {
    __shared__ float Wl[128 * 64];
    for (int i = threadIdx.x; i < 128 * 64; i += 256) Wl[i] = Wemb[i];
    __syncthreads();
    int c = threadIdx.x & 63;
    int wid = blockIdx.x * 4 + (threadIdx.x >> 6);
    int wstride = gridDim.x * 4;
    float bias = bemb[c];
    for (int base = wid * 4; base < N; base += wstride * 4) {
        int n0 = base, n1 = min(base + 1, N - 1), n2 = min(base + 2, N - 1), n3 = min(base + 3, N - 1);
        const float4* f0 = (const float4*)(nf + (size_t)n0 * FEAT);
        const float4* f1 = (const float4*)(nf + (size_t)n1 * FEAT);
        const float4* f2 = (const float4*)(nf + (size_t)n2 * FEAT);
        const float4* f3 = (const float4*)(nf + (size_t)n3 * FEAT);
        const float4* g0 = (const float4*)(act + (size_t)n0 * ACTF);
        const float4* g1 = (const float4*)(act + (size_t)n1 * ACTF);
        const float4* g2 = (const float4*)(act + (size_t)n2 * ACTF);
        const float4* g3 = (const float4*)(act + (size_t)n3 * ACTF);
        float a0 = bias, a1 = bias, a2 = bias, a3 = bias;
        #pragma unroll
        for (int kq = 0; kq < 32; ++kq) {
            float4 x0v, x1v, x2v, x3v;
            if (kq < 24) { x0v = f0[kq]; x1v = f1[kq]; x2v = f2[kq]; x3v = f3[kq]; }
            else         { x0v = g0[kq - 24]; x1v = g1[kq - 24]; x2v = g2[kq - 24]; x3v = g3[kq - 24]; }
            float w0 = Wl[(4 * kq + 0) * 64 + c];
            float w1 = Wl[(4 * kq + 1) * 64 + c];
            float w2 = Wl[(4 * kq + 2) * 64 + c];
            float w3 = Wl[(4 * kq + 3) * 64 + c];
            a0 = fmaf(x0v.x, w0, fmaf(x0v.y, w1, fmaf(x0v.z, w2, fmaf(x0v.w, w3, a0))));
            a1 = fmaf(x1v.x, w0, fmaf(x1v.y, w1, fmaf(x1v.z, w2, fmaf(x1v.w, w3, a1))));
            a2 = fmaf(x2v.x, w0, fmaf(x2v.y, w1, fmaf(x2v.z, w2, fmaf(x2v.w, w3, a2))));
            a3 = fmaf(x3v.x, w0, fmaf(x3v.y, w1, fmaf(x3v.z, w2, fmaf(x3v.w, w3, a3))));
        }
        x0[(size_t)n0 * 64 + c] = a0;
        if (base + 1 < N) x0[(size_t)n1 * 64 + c] = a1;
        if (base + 2 < N) x0[(size_t)n2 * 64 + c] = a2;
        if (base + 3 < N) x0[(size_t)n3 * 64 + c] = a3;
    }
}

// ---------- GEMM1 + scores: h1b[N,256](bf16) = x[N,64]@W1; a_s/a_d[N,4] ----------
__global__ __launch_bounds__(256) void gemm1_scores(
    const float* __restrict__ x, const float* __restrict__ W,
    const float* __restrict__ att_s, const float* __restrict__ att_d,
    __hip_bfloat16* __restrict__ h1b, float* __restrict__ a_s,
    float* __restrict__ a_d, int N) {
    int t = threadIdx.x;
    int head = t >> 6, lane = t & 63;
    float wk[64];
    #pragma unroll
    for (int k = 0; k < 64; ++k) wk[k] = W[k * 256 + t];
    float asw = att_s[t], adw = att_d[t];
    for (int node = blockIdx.x; node < N; node += gridDim.x) {
        const float4* xr = (const float4*)(x + (size_t)node * 64);
        float a0 = 0.f, a1 = 0.f, a2 = 0.f, a3 = 0.f;
        #pragma unroll
        for (int kq = 0; kq < 16; ++kq) {
            float4 xv = xr[kq];
            a0 = fmaf(xv.x, wk[4 * kq + 0], a0);
            a1 = fmaf(xv.y, wk[4 * kq + 1], a1);
            a2 = fmaf(xv.z, wk[4 * kq + 2], a2);
            a3 = fmaf(xv.w, wk[4 * kq + 3], a3);
        }
        float acc = (a0 + a1) + (a2 + a3);
        h1b[(size_t)node * 256 + t] = __float2bfloat16(acc);
        float vs = acc * asw, vd = acc * adw;
        #pragma unroll
        for (int o = 32; o; o >>= 1) {
            vs += __shfl_down(vs, o);
            vd += __shfl_down(vd, o);
        }
        if (lane == 0) {
            a_s[(size_t)node * 4 + head] = vs;
            a_d[(size_t)node * 4 + head] = vd;
        }
    }
}

// ---------- W2 -> bf16, transposed: w2t[c][k] = bf16(W2[k][c]) ----------
__global__ void w2_prep(const float* __restrict__ W2, __hip_bfloat16* __restrict__ w2t) {
    int i = blockIdx.x * 256 + threadIdx.x;   // 16384 total
    int k = i >> 6, c = i & 63;
    w2t[(size_t)c * 256 + k] = __float2bfloat16(W2[i]);
}

// ---------- GEMM2 via MFMA: h2b[N,64] = out1b[N,256] @ W2; scores fused ----------
// One wave per 16-node tile, 4 waves/block. A: out1b rows; B: w2t (col-major).
// 16x16x32 bf16 MFMA: A lane: row=l&15, k=kg*8+j; D lane: col=l&15, row=kg*4+reg.
__global__ __launch_bounds__(256) void gemm2_mfma(
    const __hip_bfloat16* __restrict__ out1b, const __hip_bfloat16* __restrict__ w2t,
    const float* __restrict__ att_s, const float* __restrict__ att_d,
    __hip_bfloat16* __restrict__ h2b, float* __restrict__ a_s, float* __restrict__ a_d,
    int N) {
    int w = threadIdx.x >> 6, l = threadIdx.x & 63;
    int nb = (blockIdx.x * 4 + w) * 16;
    if (nb >= N) return;
    int r16 = l & 15, kg = l >> 4;
    // A fragments (8 K-steps), row nb+r16
    const short* A = (const short*)out1b;
    int arow = min(nb + r16, N - 1);
    const short* arp = A + (size_t)arow * 256 + kg * 8;
    frag8 a[8];
    #pragma unroll
    for (int ks = 0; ks < 8; ++ks) a[ks] = *(const frag8*)(arp + ks * 32);
    const short* B = (const short*)w2t;
    f32x4 acc[4];
    #pragma unroll
    for (int ct = 0; ct < 4; ++ct) {
        acc[ct] = (f32x4){0.f, 0.f, 0.f, 0.f};
        const short* brp = B + (size_t)(ct * 16 + r16) * 256 + kg * 8;
        #pragma unroll
        for (int ks = 0; ks < 8; ++ks) {
            frag8 b = *(const frag8*)(brp + ks * 32);
            acc[ct] = __builtin_amdgcn_mfma_f32_16x16x32_bf16(a[ks], b, acc[ct], 0, 0, 0);
        }
    }
    // epilogue: store h2b + fused attention scores
    float s_s[4] = {0.f, 0.f, 0.f, 0.f}, s_d[4] = {0.f, 0.f, 0.f, 0.f};
    #pragma unroll
    for (int ct = 0; ct < 4; ++ct) {
        int ch = ct * 16 + r16;
        float aw = att_s[ch], dw = att_d[ch];
        #pragma unroll
        for (int r = 0; r < 4; ++r) {
            int node = nb + kg * 4 + r;
            float v = acc[ct][r];
            if (node < N) h2b[(size_t)node * 64 + ch] = __float2bfloat16(v);
            s_s[r] = fmaf(v, aw, s_s[r]);
            s_d[r] = fmaf(v, dw, s_d[r]);
        }
    }
    #pragma unroll
    for (int r = 0; r < 4; ++r) {
        #pragma unroll
        for (int o = 1; o < 16; o <<= 1) {
            s_s[r] += __shfl_xor(s_s[r], o);
            s_d[r] += __shfl_xor(s_d[r], o);
        }
        int node = nb + kg * 4 + r;
        if (r16 == 0 && node < N) { a_s[node] = s_s[r]; a_d[node] = s_d[r]; }
    }
}

// ---------- CSR build ----------
__global__ void hist_kernel(const int* __restrict__ dst, int* __restrict__ cnt, int E, int ET) {
    int e = blockIdx.x * blockDim.x + threadIdx.x;
    if (e >= ET) return;
    int d = (e < E) ? dst[e] : (e - E);
    atomicAdd(&cnt[d], 1);
}

__global__ void scan_kernel(const int* __restrict__ cnt, int* __restrict__ off, int n) {
    __shared__ int part[1024];
    int tid = threadIdx.x;
    int chunk = (n + 1023) >> 10;
    int lo = tid * chunk;
    int hi = lo + chunk; if (hi > n) hi = n; if (lo > n) lo = n;
    int s = 0;
    for (int i = lo; i < hi; ++i) s += cnt[i];
    part[tid] = s;
    __syncthreads();
    #pragma unroll
    for (int d = 1; d < 1024; d <<= 1) {
        int v = (tid >= d) ? part[tid - d] : 0;
        __syncthreads();
        part[tid] += v;
        __syncthreads();
    }
    int run = (tid == 0) ? 0 : part[tid - 1];
    for (int i = lo; i < hi; ++i) { off[i] = run; run += cnt[i]; }
    if (tid == 1023) off[n] = part[1023];
}

__global__ void scatter_kernel(const int* __restrict__ src, const int* __restrict__ dst,
                               const int* __restrict__ off, int* __restrict__ cur,
                               int* __restrict__ perm, int E, int ET) {
    int e = blockIdx.x * blockDim.x + threadIdx.x;
    if (e >= ET) return;
    int s = (e < E) ? src[e] : (e - E);
    int d = (e < E) ? dst[e] : (e - E);
    int r = atomicAdd(&cur[d], 1);
    perm[off[d] + r] = s;
}

// ---------- fused GAT layer 1 (H=4): one wave per dst, 4 dst/block ----------
__global__ __launch_bounds__(256) void fused_gat4(
    const int* __restrict__ off, const int* __restrict__ perm,
    const float* __restrict__ a_s, const float* __restrict__ a_d,
    const __hip_bfloat16* __restrict__ h1b, const float* __restrict__ bias,
    __hip_bfloat16* __restrict__ out1b, int N) {
    __shared__ float exls[4][64][4];
    __shared__ unsigned idxls[4][64];
    int w = threadIdx.x >> 6, l = threadIdx.x & 63;
    int d = blockIdx.x * 4 + w;
    if (d >= N) return;
    int lo = off[d], hi = off[d + 1];
    const float4* as4 = (const float4*)a_s;
    float4 ad = ((const float4*)a_d)[d];
    float dx = 0.f, dy = 0.f, dz = 0.f, dw = 0.f;
    for (int e = lo + l; e < hi; e += 64) {
        float4 a = as4[perm[e]];
        dx += expc(lrelu(a.x + ad.x));
        dy += expc(lrelu(a.y + ad.y));
        dz += expc(lrelu(a.z + ad.z));
        dw += expc(lrelu(a.w + ad.w));
    }
    #pragma unroll
    for (int o = 32; o; o >>= 1) {
        dx += __shfl_xor(dx, o); dy += __shfl_xor(dy, o);
        dz += __shfl_xor(dz, o); dw += __shfl_xor(dw, o);
    }
    int g = l >> 4;
    float rr = 1.f / ((g == 0 ? dx : g == 1 ? dy : g == 2 ? dz : dw) + 1e-16f);
    const char* hb = (const char*)h1b;
    unsigned laneoff = (unsigned)l * 8u;
    float acc0 = 0.f, acc1 = 0.f, acc2 = 0.f, acc3 = 0.f;
    for (int base = lo; base < hi; base += 64) {
        int e = base + l;
        if (e < hi) {
            int s = perm[e];
            float4 a = as4[s];
            exls[w][l][0] = expc(lrelu(a.x + ad.x));
            exls[w][l][1] = expc(lrelu(a.y + ad.y));
            exls[w][l][2] = expc(lrelu(a.z + ad.z));
            exls[w][l][3] = expc(lrelu(a.w + ad.w));
            idxls[w][l] = (unsigned)s * 512u;
        }
        int n = min(64, hi - base);
        #pragma unroll 4
        for (int i = 0; i < n; ++i) {
            float ex = exls[w][i][g];
            unsigned voff = idxls[w][i] + laneoff;
            uint2 v = *(const uint2*)(hb + voff);
            float f0 = __uint_as_float(v.x << 16);
            float f1 = __uint_as_float(v.x & 0xffff0000u);
            float f2 = __uint_as_float(v.y << 16);
            float f3 = __uint_as_float(v.y & 0xffff0000u);
            acc0 = fmaf(ex, f0, acc0);
            acc1 = fmaf(ex, f1, acc1);
            acc2 = fmaf(ex, f2, acc2);
            acc3 = fmaf(ex, f3, acc3);
        }
    }
    float4 bv = ((const float4*)bias)[l];
    ushort4 o4;
    o4.x = f2bf(fmaxf(fmaf(acc0, rr, bv.x), 0.f));
    o4.y = f2bf(fmaxf(fmaf(acc1, rr, bv.y), 0.f));
    o4.z = f2bf(fmaxf(fmaf(acc2, rr, bv.z), 0.f));
    o4.w = f2bf(fmaxf(fmaf(acc3, rr, bv.w), 0.f));
    ((ushort4*)out1b)[(size_t)d * 64 + l] = o4;
}

// ---------- fused GAT layer 2 (H=1): one wave per dst, 4 dst/block ----------
__global__ __launch_bounds__(256) void fused_gat1(
    const int* __restrict__ off, const int* __restrict__ perm,
    const float* __restrict__ a_s, const float* __restrict__ a_d,
    const __hip_bfloat16* __restrict__ h2b, const float* __restrict__ bias,
    float* __restrict__ out2, int N) {
    __shared__ float2 alds[4][64];
    int w = threadIdx.x >> 6, l = threadIdx.x & 63;
    int d = blockIdx.x * 4 + w;
    if (d >= N) return;
    int lo = off[d], hi = off[d + 1];
    float add = a_d[d];
    float den = 0.f;
    for (int e = lo + l; e < hi; e += 64)
        den += expc(lrelu(a_s[perm[e]] + add));
    #pragma unroll
    for (int o = 32; o; o >>= 1) den += __shfl_xor(den, o);
    float rr = 1.f / (den + 1e-16f);
    const char* hb = (const char*)h2b;
    unsigned laneoff = (unsigned)l * 2u;
    float acc = 0.f;
    for (int base = lo; base < hi; base += 64) {
        int e = base + l;
        if (e < hi) {
            int s = perm[e];
            float ex = expc(lrelu(a_s[s] + add));
            alds[w][l] = make_float2(ex, __uint_as_float((unsigned)s * 128u));
        }
        int n = min(64, hi - base);
        #pragma unroll 4
        for (int i = 0; i < n; ++i) {
            float2 p = alds[w][i];
            unsigned voff = __float_as_uint(p.y) + laneoff;
            unsigned u = *(const unsigned short*)(hb + voff);
            acc = fmaf(p.x, __uint_as_float(u << 16), acc);
        }
    }
    out2[(size_t)d * 64 + l] = fmaxf(fmaf(acc, rr, bias[l]), 0.f);
}

// ---------- column sum over nodes ----------
__global__ void colsum_kernel(const float* __restrict__ x, float* __restrict__ g, int N) {
    __shared__ float part[4][64];
    int c = threadIdx.x & 63;
    int r = threadIdx.x >> 6;
    float acc = 0.f;
    for (long long n = (long long)blockIdx.x * 4 + r; n < N; n += (long long)gridDim.x * 4)
        acc += x[n * 64 + c];
    part[r][c] = acc;
    __syncthreads();
    if (r == 0) {
        float v = part[0][c] + part[1][c] + part[2][c] + part[3][c];
        atomAddF(&g[c], v);
    }
}

__global__ void final_kernel(const float* __restrict__ g, const float* __restrict__ Wv,
                             const float* __restrict__ bv, float* __restrict__ out, int N) {
    int lane = threadIdx.x;
    float v = (g[lane] / (float)N) * Wv[lane];
    #pragma unroll
    for (int off = 32; off; off >>= 1) v += __shfl_down(v, off);
    if (lane == 0) out[0] = v + bv[0];
}

extern "C" void kernel_launch(void* const* d_in, const int* in_sizes, int n_in,
                              void* d_out, int out_size, void* d_ws, size_t ws_size,
                              hipStream_t stream) {
    const float* nf   = (const float*)d_in[0];
    const float* act  = (const float*)d_in[1];
    const int*   ei   = (const int*)d_in[2];
    const float* Wemb = (const float*)d_in[3];
    const float* bemb = (const float*)d_in[4];
    const float* W1   = (const float*)d_in[5];
    const float* as1  = (const float*)d_in[6];
    const float* ad1  = (const float*)d_in[7];
    const float* b1   = (const float*)d_in[8];
    const float* W2   = (const float*)d_in[9];
    const float* as2  = (const float*)d_in[10];
    const float* ad2  = (const float*)d_in[11];
    const float* b2   = (const float*)d_in[12];
    const float* Wv   = (const float*)d_in[13];
    const float* bv   = (const float*)d_in[14];
    float* out = (float*)d_out;

    const int N = in_sizes[0] / FEAT;
    const int E = in_sizes[2] / 2;
    const int ET = E + N;
    const int* srcp = ei;
    const int* dstp = ei + E;

    // ---- workspace layout ----
    float* ws = (float*)d_ws;
    float* x0 = ws;                                                  // N*64 f32
    __hip_bfloat16* h1b   = (__hip_bfloat16*)(x0 + (size_t)N * 64);  // N*256 bf16
    __hip_bfloat16* out1b = h1b + (size_t)N * 256;                   // N*256 bf16
    float* a_s  = (float*)(out1b + (size_t)N * 256);                 // N*4
    float* a_d  = a_s + (size_t)N * 4;                               // N*4
    __hip_bfloat16* h2b = (__hip_bfloat16*)(a_d + (size_t)N * 4);    // N*64 bf16
    float* out2 = (float*)(h2b + (size_t)N * 64);                    // N*64 f32
    float* g    = out2 + (size_t)N * 64;                             // 64
    __hip_bfloat16* w2t = (__hip_bfloat16*)(g + 64);                 // 64*256 bf16
    // CSR carved from x0 region (x0 dead after gemm1_scores)
    int* cnt  = (int*)x0;        // N
    int* off  = cnt + N;         // N+1
    int* cur  = off + N + 1;     // N
    int* perm = cur + N;         // ET

    (void)ws_size; (void)n_in; (void)out_size;

    // ---- embedding ----
    emb_kernel<<<512, 256, 0, stream>>>(nf, act, Wemb, bemb, x0, N);

    // ---- GAT layer 1: GEMM + scores (writes bf16 h1b) ----
    gemm1_scores<<<2048, 256, 0, stream>>>(x0, W1, as1, ad1, h1b, a_s, a_d, N);

    // ---- CSR build (x0 now dead) + W2 prep ----
    hipMemsetAsync(cnt, 0, (size_t)N * sizeof(int), stream);
    hipMemsetAsync(cur, 0, (size_t)N * sizeof(int), stream);
    hist_kernel<<<(ET + 255) / 256, 256, 0, stream>>>(dstp, cnt, E, ET);
    scan_kernel<<<1, 1024, 0, stream>>>(cnt, off, N);
    scatter_kernel<<<(ET + 255) / 256, 256, 0, stream>>>(srcp, dstp, off, cur, perm, E, ET);
    w2_prep<<<64, 256, 0, stream>>>(W2, w2t);

    // ---- GAT layer 1: fused softmax + aggregate + bias + relu (bf16 out) ----
    fused_gat4<<<(N + 3) / 4, 256, 0, stream>>>(off, perm, a_s, a_d, h1b, b1, out1b, N);

    // ---- GAT layer 2: MFMA GEMM + scores, then fused aggregate ----
    gemm2_mfma<<<(N + 63) / 64, 256, 0, stream>>>(out1b, w2t, as2, ad2, h2b, a_s, a_d, N);
    fused_gat1<<<(N + 3) / 4, 256, 0, stream>>>(off, perm, a_s, a_d, h2b, b2, out2, N);

    // ---- readout ----
    hipMemsetAsync(g, 0, 64 * sizeof(float), stream);
    colsum_kernel<<<512, 256, 0, stream>>>(out2, g, N);
    final_kernel<<<1, 64, 0, stream>>>(g, Wv, bv, out, N);
}

// Round 10
// 422.642 us; speedup vs baseline: 1.0955x; 1.0955x over previous
//
#include <hip/hip_runtime.h>
#include <hip/hip_bf16.h>
#include <math.h>

#define FEAT 96
#define ACTF 32

using frag8 = __attribute__((ext_vector_type(8))) short;   // 8 bf16 (4 VGPRs)
using f32x4 = __attribute__((ext_vector_type(4))) float;

__device__ __forceinline__ float lrelu(float x) { return x >= 0.f ? x : 0.2f * x; }
__device__ __forceinline__ void atomAddF(float* p, float v) {
    __hip_atomic_fetch_add(p, v, __ATOMIC_RELAXED, __HIP_MEMORY_SCOPE_AGENT);
}
__device__ __forceinline__ float expc(float x) { return __expf(fminf(x, 60.f)); }
__device__ __forceinline__ unsigned short f2bf(float f) {
    __hip_bfloat16 h = __float2bfloat16(f);
    return *(unsigned short*)&h;
}

// ---------- embedding: x0[N,64] = [nf|act] @ Wemb[128,64] + bemb ----------
// Barrier-free, low-VGPR: 2 nodes/wave, partial unroll, launch_bounds cap.
__global__ __launch_bounds__(256, 4) void emb_kernel(
    const float* __restrict__ nf, const float* __restrict__ act,
    const float* __restrict__ Wemb, const float* __restrict__ bemb,
    float* __restrict__ x0, int N) {
    __shared__ float Wl[128 * 64];
    for (int i = threadIdx.x; i < 128 * 64; i += 256) Wl[i] = Wemb[i];
    __syncthreads();
    int c = threadIdx.x & 63;
    int wid = blockIdx.x * 4 + (threadIdx.x >> 6);
    int wstride = gridDim.x * 4;
    float bias = bemb[c];
    for (int base = wid * 2; base < N; base += wstride * 2) {
        int n0 = base, n1 = min(base + 1, N - 1);
        const float4* f0 = (const float4*)(nf + (size_t)n0 * FEAT);
        const float4* f1 = (const float4*)(nf + (size_t)n1 * FEAT);
        const float4* g0 = (const float4*)(act + (size_t)n0 * ACTF);
        const float4* g1 = (const float4*)(act + (size_t)n1 * ACTF);
        float a0 = bias, a1 = bias;
        #pragma unroll 4
        for (int kq = 0; kq < 24; ++kq) {
            float4 x0v = f0[kq], x1v = f1[kq];
            float w0 = Wl[(4 * kq + 0) * 64 + c];
            float w1 = Wl[(4 * kq + 1) * 64 + c];
            float w2 = Wl[(4 * kq + 2) * 64 + c];
            float w3 = Wl[(4 * kq + 3) * 64 + c];
            a0 = fmaf(x0v.x, w0, fmaf(x0v.y, w1, fmaf(x0v.z, w2, fmaf(x0v.w, w3, a0))));
            a1 = fmaf(x1v.x, w0, fmaf(x1v.y, w1, fmaf(x1v.z, w2, fmaf(x1v.w, w3, a1))));
        }
        #pragma unroll 4
        for (int kq = 0; kq < 8; ++kq) {
            float4 x0v = g0[kq], x1v = g1[kq];
            float w0 = Wl[(96 + 4 * kq + 0) * 64 + c];
            float w1 = Wl[(96 + 4 * kq + 1) * 64 + c];
            float w2 = Wl[(96 + 4 * kq + 2) * 64 + c];
            float w3 = Wl[(96 + 4 * kq + 3) * 64 + c];
            a0 = fmaf(x0v.x, w0, fmaf(x0v.y, w1, fmaf(x0v.z, w2, fmaf(x0v.w, w3, a0))));
            a1 = fmaf(x1v.x, w0, fmaf(x1v.y, w1, fmaf(x1v.z, w2, fmaf(x1v.w, w3, a1))));
        }
        x0[(size_t)n0 * 64 + c] = a0;
        if (base + 1 < N) x0[(size_t)n1 * 64 + c] = a1;
    }
}

// ---------- GEMM1 + scores: h1b[N,256](bf16) = x[N,64]@W1; a_s/a_d[N,4] ----------
__global__ __launch_bounds__(256) void gemm1_scores(
    const float* __restrict__ x, const float* __restrict__ W,
    const float* __restrict__ att_s, const float* __restrict__ att_d,
    __hip_bfloat16* __restrict__ h1b, float* __restrict__ a_s,
    float* __restrict__ a_d, int N) {
    int t = threadIdx.x;
    int head = t >> 6, lane = t & 63;
    float wk[64];
    #pragma unroll
    for (int k = 0; k < 64; ++k) wk[k] = W[k * 256 + t];
    float asw = att_s[t], adw = att_d[t];
    for (int node = blockIdx.x; node < N; node += gridDim.x) {
        const float4* xr = (const float4*)(x + (size_t)node * 64);
        float a0 = 0.f, a1 = 0.f, a2 = 0.f, a3 = 0.f;
        #pragma unroll
        for (int kq = 0; kq < 16; ++kq) {
            float4 xv = xr[kq];
            a0 = fmaf(xv.x, wk[4 * kq + 0], a0);
            a1 = fmaf(xv.y, wk[4 * kq + 1], a1);
            a2 = fmaf(xv.z, wk[4 * kq + 2], a2);
            a3 = fmaf(xv.w, wk[4 * kq + 3], a3);
        }
        float acc = (a0 + a1) + (a2 + a3);
        h1b[(size_t)node * 256 + t] = __float2bfloat16(acc);
        float vs = acc * asw, vd = acc * adw;
        #pragma unroll
        for (int o = 32; o; o >>= 1) {
            vs += __shfl_down(vs, o);
            vd += __shfl_down(vd, o);
        }
        if (lane == 0) {
            a_s[(size_t)node * 4 + head] = vs;
            a_d[(size_t)node * 4 + head] = vd;
        }
    }
}

// ---------- W2 -> bf16, transposed: w2t[c][k] = bf16(W2[k][c]) ----------
__global__ void w2_prep(const float* __restrict__ W2, __hip_bfloat16* __restrict__ w2t) {
    int i = blockIdx.x * 256 + threadIdx.x;   // 16384 total
    int k = i >> 6, c = i & 63;
    w2t[(size_t)c * 256 + k] = __float2bfloat16(W2[i]);
}

// ---------- GEMM2 via MFMA: h2b[N,64] = out1b[N,256] @ W2; scores fused ----------
__global__ __launch_bounds__(256) void gemm2_mfma(
    const __hip_bfloat16* __restrict__ out1b, const __hip_bfloat16* __restrict__ w2t,
    const float* __restrict__ att_s, const float* __restrict__ att_d,
    __hip_bfloat16* __restrict__ h2b, float* __restrict__ a_s, float* __restrict__ a_d,
    int N) {
    int w = threadIdx.x >> 6, l = threadIdx.x & 63;
    int nb = (blockIdx.x * 4 + w) * 16;
    if (nb >= N) return;
    int r16 = l & 15, kg = l >> 4;
    const short* A = (const short*)out1b;
    int arow = min(nb + r16, N - 1);
    const short* arp = A + (size_t)arow * 256 + kg * 8;
    frag8 a[8];
    #pragma unroll
    for (int ks = 0; ks < 8; ++ks) a[ks] = *(const frag8*)(arp + ks * 32);
    const short* B = (const short*)w2t;
    f32x4 acc[4];
    #pragma unroll
    for (int ct = 0; ct < 4; ++ct) {
        acc[ct] = (f32x4){0.f, 0.f, 0.f, 0.f};
        const short* brp = B + (size_t)(ct * 16 + r16) * 256 + kg * 8;
        #pragma unroll
        for (int ks = 0; ks < 8; ++ks) {
            frag8 b = *(const frag8*)(brp + ks * 32);
            acc[ct] = __builtin_amdgcn_mfma_f32_16x16x32_bf16(a[ks], b, acc[ct], 0, 0, 0);
        }
    }
    float s_s[4] = {0.f, 0.f, 0.f, 0.f}, s_d[4] = {0.f, 0.f, 0.f, 0.f};
    #pragma unroll
    for (int ct = 0; ct < 4; ++ct) {
        int ch = ct * 16 + r16;
        float aw = att_s[ch], dw = att_d[ch];
        #pragma unroll
        for (int r = 0; r < 4; ++r) {
            int node = nb + kg * 4 + r;
            float v = acc[ct][r];
            if (node < N) h2b[(size_t)node * 64 + ch] = __float2bfloat16(v);
            s_s[r] = fmaf(v, aw, s_s[r]);
            s_d[r] = fmaf(v, dw, s_d[r]);
        }
    }
    #pragma unroll
    for (int r = 0; r < 4; ++r) {
        #pragma unroll
        for (int o = 1; o < 16; o <<= 1) {
            s_s[r] += __shfl_xor(s_s[r], o);
            s_d[r] += __shfl_xor(s_d[r], o);
        }
        int node = nb + kg * 4 + r;
        if (r16 == 0 && node < N) { a_s[node] = s_s[r]; a_d[node] = s_d[r]; }
    }
}

// ---------- CSR build ----------
__global__ void hist_kernel(const int* __restrict__ dst, int* __restrict__ cnt, int E, int ET) {
    int e = blockIdx.x * blockDim.x + threadIdx.x;
    if (e >= ET) return;
    int d = (e < E) ? dst[e] : (e - E);
    atomicAdd(&cnt[d], 1);
}

__global__ void scan_kernel(const int* __restrict__ cnt, int* __restrict__ off, int n) {
    __shared__ int part[1024];
    int tid = threadIdx.x;
    int chunk = (n + 1023) >> 10;
    int lo = tid * chunk;
    int hi = lo + chunk; if (hi > n) hi = n; if (lo > n) lo = n;
    int s = 0;
    for (int i = lo; i < hi; ++i) s += cnt[i];
    part[tid] = s;
    __syncthreads();
    #pragma unroll
    for (int d = 1; d < 1024; d <<= 1) {
        int v = (tid >= d) ? part[tid - d] : 0;
        __syncthreads();
        part[tid] += v;
        __syncthreads();
    }
    int run = (tid == 0) ? 0 : part[tid - 1];
    for (int i = lo; i < hi; ++i) { off[i] = run; run += cnt[i]; }
    if (tid == 1023) off[n] = part[1023];
}

__global__ void scatter_kernel(const int* __restrict__ src, const int* __restrict__ dst,
                               const int* __restrict__ off, int* __restrict__ cur,
                               int* __restrict__ perm, int E, int ET) {
    int e = blockIdx.x * blockDim.x + threadIdx.x;
    if (e >= ET) return;
    int s = (e < E) ? src[e] : (e - E);
    int d = (e < E) ? dst[e] : (e - E);
    int r = atomicAdd(&cur[d], 1);
    perm[off[d] + r] = s;
}

// ---------- fused GAT layer 1 (H=4): one wave per dst, 4 dst/block ----------
__global__ __launch_bounds__(256) void fused_gat4(
    const int* __restrict__ off, const int* __restrict__ perm,
    const float* __restrict__ a_s, const float* __restrict__ a_d,
    const __hip_bfloat16* __restrict__ h1b, const float* __restrict__ bias,
    __hip_bfloat16* __restrict__ out1b, int N) {
    __shared__ float exls[4][64][4];
    __shared__ unsigned idxls[4][64];
    int w = threadIdx.x >> 6, l = threadIdx.x & 63;
    int d = blockIdx.x * 4 + w;
    if (d >= N) return;
    int lo = off[d], hi = off[d + 1];
    const float4* as4 = (const float4*)a_s;
    float4 ad = ((const float4*)a_d)[d];
    float dx = 0.f, dy = 0.f, dz = 0.f, dw = 0.f;
    for (int e = lo + l; e < hi; e += 64) {
        float4 a = as4[perm[e]];
        dx += expc(lrelu(a.x + ad.x));
        dy += expc(lrelu(a.y + ad.y));
        dz += expc(lrelu(a.z + ad.z));
        dw += expc(lrelu(a.w + ad.w));
    }
    #pragma unroll
    for (int o = 32; o; o >>= 1) {
        dx += __shfl_xor(dx, o); dy += __shfl_xor(dy, o);
        dz += __shfl_xor(dz, o); dw += __shfl_xor(dw, o);
    }
    int g = l >> 4;
    float rr = 1.f / ((g == 0 ? dx : g == 1 ? dy : g == 2 ? dz : dw) + 1e-16f);
    const char* hb = (const char*)h1b;
    unsigned laneoff = (unsigned)l * 8u;
    float acc0 = 0.f, acc1 = 0.f, acc2 = 0.f, acc3 = 0.f;
    for (int base = lo; base < hi; base += 64) {
        int e = base + l;
        if (e < hi) {
            int s = perm[e];
            float4 a = as4[s];
            exls[w][l][0] = expc(lrelu(a.x + ad.x));
            exls[w][l][1] = expc(lrelu(a.y + ad.y));
            exls[w][l][2] = expc(lrelu(a.z + ad.z));
            exls[w][l][3] = expc(lrelu(a.w + ad.w));
            idxls[w][l] = (unsigned)s * 512u;
        }
        int n = min(64, hi - base);
        #pragma unroll 4
        for (int i = 0; i < n; ++i) {
            float ex = exls[w][i][g];
            unsigned voff = idxls[w][i] + laneoff;
            uint2 v = *(const uint2*)(hb + voff);
            float f0 = __uint_as_float(v.x << 16);
            float f1 = __uint_as_float(v.x & 0xffff0000u);
            float f2 = __uint_as_float(v.y << 16);
            float f3 = __uint_as_float(v.y & 0xffff0000u);
            acc0 = fmaf(ex, f0, acc0);
            acc1 = fmaf(ex, f1, acc1);
            acc2 = fmaf(ex, f2, acc2);
            acc3 = fmaf(ex, f3, acc3);
        }
    }
    float4 bv = ((const float4*)bias)[l];
    ushort4 o4;
    o4.x = f2bf(fmaxf(fmaf(acc0, rr, bv.x), 0.f));
    o4.y = f2bf(fmaxf(fmaf(acc1, rr, bv.y), 0.f));
    o4.z = f2bf(fmaxf(fmaf(acc2, rr, bv.z), 0.f));
    o4.w = f2bf(fmaxf(fmaf(acc3, rr, bv.w), 0.f));
    ((ushort4*)out1b)[(size_t)d * 64 + l] = o4;
}

// ---------- fused GAT layer 2 (H=1): one wave per dst, 4 dst/block ----------
__global__ __launch_bounds__(256) void fused_gat1(
    const int* __restrict__ off, const int* __restrict__ perm,
    const float* __restrict__ a_s, const float* __restrict__ a_d,
    const __hip_bfloat16* __restrict__ h2b, const float* __restrict__ bias,
    float* __restrict__ out2, int N) {
    __shared__ float2 alds[4][64];
    int w = threadIdx.x >> 6, l = threadIdx.x & 63;
    int d = blockIdx.x * 4 + w;
    if (d >= N) return;
    int lo = off[d], hi = off[d + 1];
    float add = a_d[d];
    float den = 0.f;
    for (int e = lo + l; e < hi; e += 64)
        den += expc(lrelu(a_s[perm[e]] + add));
    #pragma unroll
    for (int o = 32; o; o >>= 1) den += __shfl_xor(den, o);
    float rr = 1.f / (den + 1e-16f);
    const char* hb = (const char*)h2b;
    unsigned laneoff = (unsigned)l * 2u;
    float acc = 0.f;
    for (int base = lo; base < hi; base += 64) {
        int e = base + l;
        if (e < hi) {
            int s = perm[e];
            float ex = expc(lrelu(a_s[s] + add));
            alds[w][l] = make_float2(ex, __uint_as_float((unsigned)s * 128u));
        }
        int n = min(64, hi - base);
        #pragma unroll 4
        for (int i = 0; i < n; ++i) {
            float2 p = alds[w][i];
            unsigned voff = __float_as_uint(p.y) + laneoff;
            unsigned u = *(const unsigned short*)(hb + voff);
            acc = fmaf(p.x, __uint_as_float(u << 16), acc);
        }
    }
    out2[(size_t)d * 64 + l] = fmaxf(fmaf(acc, rr, bias[l]), 0.f);
}

// ---------- column sum over nodes ----------
__global__ void colsum_kernel(const float* __restrict__ x, float* __restrict__ g, int N) {
    __shared__ float part[4][64];
    int c = threadIdx.x & 63;
    int r = threadIdx.x >> 6;
    float acc = 0.f;
    for (long long n = (long long)blockIdx.x * 4 + r; n < N; n += (long long)gridDim.x * 4)
        acc += x[n * 64 + c];
    part[r][c] = acc;
    __syncthreads();
    if (r == 0) {
        float v = part[0][c] + part[1][c] + part[2][c] + part[3][c];
        atomAddF(&g[c], v);
    }
}

__global__ void final_kernel(const float* __restrict__ g, const float* __restrict__ Wv,
                             const float* __restrict__ bv, float* __restrict__ out, int N) {
    int lane = threadIdx.x;
    float v = (g[lane] / (float)N) * Wv[lane];
    #pragma unroll
    for (int off = 32; off; off >>= 1) v += __shfl_down(v, off);
    if (lane == 0) out[0] = v + bv[0];
}

extern "C" void kernel_launch(void* const* d_in, const int* in_sizes, int n_in,
                              void* d_out, int out_size, void* d_ws, size_t ws_size,
                              hipStream_t stream) {
    const float* nf   = (const float*)d_in[0];
    const float* act  = (const float*)d_in[1];
    const int*   ei   = (const int*)d_in[2];
    const float* Wemb = (const float*)d_in[3];
    const float* bemb = (const float*)d_in[4];
    const float* W1   = (const float*)d_in[5];
    const float* as1  = (const float*)d_in[6];
    const float* ad1  = (const float*)d_in[7];
    const float* b1   = (const float*)d_in[8];
    const float* W2   = (const float*)d_in[9];
    const float* as2  = (const float*)d_in[10];
    const float* ad2  = (const float*)d_in[11];
    const float* b2   = (const float*)d_in[12];
    const float* Wv   = (const float*)d_in[13];
    const float* bv   = (const float*)d_in[14];
    float* out = (float*)d_out;

    const int N = in_sizes[0] / FEAT;
    const int E = in_sizes[2] / 2;
    const int ET = E + N;
    const int* srcp = ei;
    const int* dstp = ei + E;

    // ---- workspace layout ----
    float* ws = (float*)d_ws;
    float* x0 = ws;                                                  // N*64 f32
    __hip_bfloat16* h1b   = (__hip_bfloat16*)(x0 + (size_t)N * 64);  // N*256 bf16
    __hip_bfloat16* out1b = h1b + (size_t)N * 256;                   // N*256 bf16
    float* a_s  = (float*)(out1b + (size_t)N * 256);                 // N*4
    float* a_d  = a_s + (size_t)N * 4;                               // N*4
    __hip_bfloat16* h2b = (__hip_bfloat16*)(a_d + (size_t)N * 4);    // N*64 bf16
    float* out2 = (float*)(h2b + (size_t)N * 64);                    // N*64 f32
    float* g    = out2 + (size_t)N * 64;                             // 64
    __hip_bfloat16* w2t = (__hip_bfloat16*)(g + 64);                 // 64*256 bf16
    // CSR carved from x0 region (x0 dead after gemm1_scores)
    int* cnt  = (int*)x0;        // N
    int* off  = cnt + N;         // N+1
    int* cur  = off + N + 1;     // N
    int* perm = cur + N;         // ET

    (void)ws_size; (void)n_in; (void)out_size;

    // ---- embedding ----
    emb_kernel<<<2048, 256, 0, stream>>>(nf, act, Wemb, bemb, x0, N);

    // ---- GAT layer 1: GEMM + scores (writes bf16 h1b) ----
    gemm1_scores<<<2048, 256, 0, stream>>>(x0, W1, as1, ad1, h1b, a_s, a_d, N);

    // ---- CSR build (x0 now dead) + W2 prep ----
    hipMemsetAsync(cnt, 0, (size_t)N * sizeof(int), stream);
    hipMemsetAsync(cur, 0, (size_t)N * sizeof(int), stream);
    hist_kernel<<<(ET + 255) / 256, 256, 0, stream>>>(dstp, cnt, E, ET);
    scan_kernel<<<1, 1024, 0, stream>>>(cnt, off, N);
    scatter_kernel<<<(ET + 255) / 256, 256, 0, stream>>>(srcp, dstp, off, cur, perm, E, ET);
    w2_prep<<<64, 256, 0, stream>>>(W2, w2t);

    // ---- GAT layer 1: fused softmax + aggregate + bias + relu (bf16 out) ----
    fused_gat4<<<(N + 3) / 4, 256, 0, stream>>>(off, perm, a_s, a_d, h1b, b1, out1b, N);

    // ---- GAT layer 2: MFMA GEMM + scores, then fused aggregate ----
    gemm2_mfma<<<(N + 63) / 64, 256, 0, stream>>>(out1b, w2t, as2, ad2, h2b, a_s, a_d, N);
    fused_gat1<<<(N + 3) / 4, 256, 0, stream>>>(off, perm, a_s, a_d, h2b, b2, out2, N);

    // ---- readout ----
    hipMemsetAsync(g, 0, 64 * sizeof(float), stream);
    colsum_kernel<<<512, 256, 0, stream>>>(out2, g, N);
    final_kernel<<<1, 64, 0, stream>>>(g, Wv, bv, out, N);
}

// Round 11
// 359.610 us; speedup vs baseline: 1.2875x; 1.1753x over previous
//
#include <hip/hip_runtime.h>
#include <hip/hip_bf16.h>
#include <math.h>

#define FEAT 96
#define ACTF 32

using frag8 = __attribute__((ext_vector_type(8))) short;   // 8 bf16 (4 VGPRs)
using f32x4 = __attribute__((ext_vector_type(4))) float;

__device__ __forceinline__ float lrelu(float x) { return x >= 0.f ? x : 0.2f * x; }
__device__ __forceinline__ void atomAddF(float* p, float v) {
    __hip_atomic_fetch_add(p, v, __ATOMIC_RELAXED, __HIP_MEMORY_SCOPE_AGENT);
}
__device__ __forceinline__ float expc(float x) { return __expf(fminf(x, 60.f)); }
__device__ __forceinline__ unsigned short f2bf(float f) {
    __hip_bfloat16 h = __float2bfloat16(f);
    return *(unsigned short*)&h;
}

// ---------- embedding: x0[N,64] = [nf|act] @ Wemb[128,64] + bemb ----------
__global__ __launch_bounds__(256, 4) void emb_kernel(
    const float* __restrict__ nf, const float* __restrict__ act,
    const float* __restrict__ Wemb, const float* __restrict__ bemb,
    float* __restrict__ x0, int N) {
    __shared__ float Wl[128 * 64];
    for (int i = threadIdx.x; i < 128 * 64; i += 256) Wl[i] = Wemb[i];
    __syncthreads();
    int c = threadIdx.x & 63;
    int wid = blockIdx.x * 4 + (threadIdx.x >> 6);
    int wstride = gridDim.x * 4;
    float bias = bemb[c];
    for (int base = wid * 2; base < N; base += wstride * 2) {
        int n0 = base, n1 = min(base + 1, N - 1);
        const float4* f0 = (const float4*)(nf + (size_t)n0 * FEAT);
        const float4* f1 = (const float4*)(nf + (size_t)n1 * FEAT);
        const float4* g0 = (const float4*)(act + (size_t)n0 * ACTF);
        const float4* g1 = (const float4*)(act + (size_t)n1 * ACTF);
        float a0 = bias, a1 = bias;
        #pragma unroll 4
        for (int kq = 0; kq < 24; ++kq) {
            float4 x0v = f0[kq], x1v = f1[kq];
            float w0 = Wl[(4 * kq + 0) * 64 + c];
            float w1 = Wl[(4 * kq + 1) * 64 + c];
            float w2 = Wl[(4 * kq + 2) * 64 + c];
            float w3 = Wl[(4 * kq + 3) * 64 + c];
            a0 = fmaf(x0v.x, w0, fmaf(x0v.y, w1, fmaf(x0v.z, w2, fmaf(x0v.w, w3, a0))));
            a1 = fmaf(x1v.x, w0, fmaf(x1v.y, w1, fmaf(x1v.z, w2, fmaf(x1v.w, w3, a1))));
        }
        #pragma unroll 4
        for (int kq = 0; kq < 8; ++kq) {
            float4 x0v = g0[kq], x1v = g1[kq];
            float w0 = Wl[(96 + 4 * kq + 0) * 64 + c];
            float w1 = Wl[(96 + 4 * kq + 1) * 64 + c];
            float w2 = Wl[(96 + 4 * kq + 2) * 64 + c];
            float w3 = Wl[(96 + 4 * kq + 3) * 64 + c];
            a0 = fmaf(x0v.x, w0, fmaf(x0v.y, w1, fmaf(x0v.z, w2, fmaf(x0v.w, w3, a0))));
            a1 = fmaf(x1v.x, w0, fmaf(x1v.y, w1, fmaf(x1v.z, w2, fmaf(x1v.w, w3, a1))));
        }
        x0[(size_t)n0 * 64 + c] = a0;
        if (base + 1 < N) x0[(size_t)n1 * 64 + c] = a1;
    }
}

// ---------- GEMM1 + scores: h1b[N,256](bf16) = x[N,64]@W1; a_s/a_d[N,4] ----------
__global__ __launch_bounds__(256) void gemm1_scores(
    const float* __restrict__ x, const float* __restrict__ W,
    const float* __restrict__ att_s, const float* __restrict__ att_d,
    __hip_bfloat16* __restrict__ h1b, float* __restrict__ a_s,
    float* __restrict__ a_d, int N) {
    int t = threadIdx.x;
    int head = t >> 6, lane = t & 63;
    float wk[64];
    #pragma unroll
    for (int k = 0; k < 64; ++k) wk[k] = W[k * 256 + t];
    float asw = att_s[t], adw = att_d[t];
    for (int node = blockIdx.x; node < N; node += gridDim.x) {
        const float4* xr = (const float4*)(x + (size_t)node * 64);
        float a0 = 0.f, a1 = 0.f, a2 = 0.f, a3 = 0.f;
        #pragma unroll
        for (int kq = 0; kq < 16; ++kq) {
            float4 xv = xr[kq];
            a0 = fmaf(xv.x, wk[4 * kq + 0], a0);
            a1 = fmaf(xv.y, wk[4 * kq + 1], a1);
            a2 = fmaf(xv.z, wk[4 * kq + 2], a2);
            a3 = fmaf(xv.w, wk[4 * kq + 3], a3);
        }
        float acc = (a0 + a1) + (a2 + a3);
        h1b[(size_t)node * 256 + t] = __float2bfloat16(acc);
        float vs = acc * asw, vd = acc * adw;
        #pragma unroll
        for (int o = 32; o; o >>= 1) {
            vs += __shfl_down(vs, o);
            vd += __shfl_down(vd, o);
        }
        if (lane == 0) {
            a_s[(size_t)node * 4 + head] = vs;
            a_d[(size_t)node * 4 + head] = vd;
        }
    }
}

// ---------- W2 -> bf16, transposed: w2t[c][k] = bf16(W2[k][c]) ----------
__global__ void w2_prep(const float* __restrict__ W2, __hip_bfloat16* __restrict__ w2t) {
    int i = blockIdx.x * 256 + threadIdx.x;   // 16384 total
    int k = i >> 6, c = i & 63;
    w2t[(size_t)c * 256 + k] = __float2bfloat16(W2[i]);
}

// ---------- GEMM2 via MFMA: h2b[N,64] = out1b[N,256] @ W2; scores fused ----------
__global__ __launch_bounds__(256) void gemm2_mfma(
    const __hip_bfloat16* __restrict__ out1b, const __hip_bfloat16* __restrict__ w2t,
    const float* __restrict__ att_s, const float* __restrict__ att_d,
    __hip_bfloat16* __restrict__ h2b, float* __restrict__ a_s, float* __restrict__ a_d,
    int N) {
    int w = threadIdx.x >> 6, l = threadIdx.x & 63;
    int nb = (blockIdx.x * 4 + w) * 16;
    if (nb >= N) return;
    int r16 = l & 15, kg = l >> 4;
    const short* A = (const short*)out1b;
    int arow = min(nb + r16, N - 1);
    const short* arp = A + (size_t)arow * 256 + kg * 8;
    frag8 a[8];
    #pragma unroll
    for (int ks = 0; ks < 8; ++ks) a[ks] = *(const frag8*)(arp + ks * 32);
    const short* B = (const short*)w2t;
    f32x4 acc[4];
    #pragma unroll
    for (int ct = 0; ct < 4; ++ct) {
        acc[ct] = (f32x4){0.f, 0.f, 0.f, 0.f};
        const short* brp = B + (size_t)(ct * 16 + r16) * 256 + kg * 8;
        #pragma unroll
        for (int ks = 0; ks < 8; ++ks) {
            frag8 b = *(const frag8*)(brp + ks * 32);
            acc[ct] = __builtin_amdgcn_mfma_f32_16x16x32_bf16(a[ks], b, acc[ct], 0, 0, 0);
        }
    }
    float s_s[4] = {0.f, 0.f, 0.f, 0.f}, s_d[4] = {0.f, 0.f, 0.f, 0.f};
    #pragma unroll
    for (int ct = 0; ct < 4; ++ct) {
        int ch = ct * 16 + r16;
        float aw = att_s[ch], dw = att_d[ch];
        #pragma unroll
        for (int r = 0; r < 4; ++r) {
            int node = nb + kg * 4 + r;
            float v = acc[ct][r];
            if (node < N) h2b[(size_t)node * 64 + ch] = __float2bfloat16(v);
            s_s[r] = fmaf(v, aw, s_s[r]);
            s_d[r] = fmaf(v, dw, s_d[r]);
        }
    }
    #pragma unroll
    for (int r = 0; r < 4; ++r) {
        #pragma unroll
        for (int o = 1; o < 16; o <<= 1) {
            s_s[r] += __shfl_xor(s_s[r], o);
            s_d[r] += __shfl_xor(s_d[r], o);
        }
        int node = nb + kg * 4 + r;
        if (r16 == 0 && node < N) { a_s[node] = s_s[r]; a_d[node] = s_d[r]; }
    }
}

// ---------- CSR build ----------
__global__ void hist_kernel(const int* __restrict__ dst, int* __restrict__ cnt, int E, int ET) {
    int e = blockIdx.x * blockDim.x + threadIdx.x;
    if (e >= ET) return;
    int d = (e < E) ? dst[e] : (e - E);
    atomicAdd(&cnt[d], 1);
}

// hierarchical scan: blocks of 256, wave shfl scan + cross-wave LDS prefix
__global__ __launch_bounds__(256) void scan_blocks(
    const int* __restrict__ cnt, int* __restrict__ off, int* __restrict__ bsum, int n) {
    int b = blockIdx.x, t = threadIdx.x;
    int i = b * 256 + t;
    int v = (i < n) ? cnt[i] : 0;
    int lane = t & 63, w = t >> 6;
    int x = v;
    #pragma unroll
    for (int o = 1; o < 64; o <<= 1) {
        int y = __shfl_up(x, o);
        if (lane >= o) x += y;
    }
    __shared__ int wtot[4];
    if (lane == 63) wtot[w] = x;
    __syncthreads();
    int add = 0;
    #pragma unroll
    for (int j = 0; j < 4; ++j) if (j < w) add += wtot[j];
    int incl = x + add;
    if (i < n) off[i] = incl - v;    // exclusive prefix within block
    if (t == 255) bsum[b] = incl;    // block total
}

__global__ __launch_bounds__(256) void scan_tops(
    const int* __restrict__ bsum, int* __restrict__ bpre, int nb) {
    int t = threadIdx.x;
    int v = (t < nb) ? bsum[t] : 0;
    int lane = t & 63, w = t >> 6;
    int x = v;
    #pragma unroll
    for (int o = 1; o < 64; o <<= 1) {
        int y = __shfl_up(x, o);
        if (lane >= o) x += y;
    }
    __shared__ int wtot[4];
    if (lane == 63) wtot[w] = x;
    __syncthreads();
    int add = 0;
    #pragma unroll
    for (int j = 0; j < 4; ++j) if (j < w) add += wtot[j];
    if (t < nb) bpre[t] = x + add - v;   // exclusive block prefix
    if (t == 255) bpre[nb] = x + add;    // grand total
}

__global__ __launch_bounds__(256) void scan_add(
    const int* __restrict__ bpre, int* __restrict__ off, int n, int nb) {
    int b = blockIdx.x, t = threadIdx.x;
    int i = b * 256 + t;
    if (i < n) off[i] += bpre[b];
    if (b == 0 && t == 0) off[n] = bpre[nb];
}

__global__ void scatter_kernel(const int* __restrict__ src, const int* __restrict__ dst,
                               const int* __restrict__ off, int* __restrict__ cur,
                               int* __restrict__ perm, int E, int ET) {
    int e = blockIdx.x * blockDim.x + threadIdx.x;
    if (e >= ET) return;
    int s = (e < E) ? src[e] : (e - E);
    int d = (e < E) ? dst[e] : (e - E);
    int r = atomicAdd(&cur[d], 1);
    perm[off[d] + r] = s;
}

// ---------- fused GAT layer 1 (H=4): one wave per dst, 4 dst/block ----------
__global__ __launch_bounds__(256) void fused_gat4(
    const int* __restrict__ off, const int* __restrict__ perm,
    const float* __restrict__ a_s, const float* __restrict__ a_d,
    const __hip_bfloat16* __restrict__ h1b, const float* __restrict__ bias,
    __hip_bfloat16* __restrict__ out1b, int N) {
    __shared__ float exls[4][64][4];
    __shared__ unsigned idxls[4][64];
    int w = threadIdx.x >> 6, l = threadIdx.x & 63;
    int d = blockIdx.x * 4 + w;
    if (d >= N) return;
    int lo = off[d], hi = off[d + 1];
    const float4* as4 = (const float4*)a_s;
    float4 ad = ((const float4*)a_d)[d];
    float dx = 0.f, dy = 0.f, dz = 0.f, dw = 0.f;
    for (int e = lo + l; e < hi; e += 64) {
        float4 a = as4[perm[e]];
        dx += expc(lrelu(a.x + ad.x));
        dy += expc(lrelu(a.y + ad.y));
        dz += expc(lrelu(a.z + ad.z));
        dw += expc(lrelu(a.w + ad.w));
    }
    #pragma unroll
    for (int o = 32; o; o >>= 1) {
        dx += __shfl_xor(dx, o); dy += __shfl_xor(dy, o);
        dz += __shfl_xor(dz, o); dw += __shfl_xor(dw, o);
    }
    int g = l >> 4;
    float rr = 1.f / ((g == 0 ? dx : g == 1 ? dy : g == 2 ? dz : dw) + 1e-16f);
    const char* hb = (const char*)h1b;
    unsigned laneoff = (unsigned)l * 8u;
    float acc0 = 0.f, acc1 = 0.f, acc2 = 0.f, acc3 = 0.f;
    for (int base = lo; base < hi; base += 64) {
        int e = base + l;
        if (e < hi) {
            int s = perm[e];
            float4 a = as4[s];
            exls[w][l][0] = expc(lrelu(a.x + ad.x));
            exls[w][l][1] = expc(lrelu(a.y + ad.y));
            exls[w][l][2] = expc(lrelu(a.z + ad.z));
            exls[w][l][3] = expc(lrelu(a.w + ad.w));
            idxls[w][l] = (unsigned)s * 512u;
        }
        int n = min(64, hi - base);
        #pragma unroll 4
        for (int i = 0; i < n; ++i) {
            float ex = exls[w][i][g];
            unsigned voff = idxls[w][i] + laneoff;
            uint2 v = *(const uint2*)(hb + voff);
            float f0 = __uint_as_float(v.x << 16);
            float f1 = __uint_as_float(v.x & 0xffff0000u);
            float f2 = __uint_as_float(v.y << 16);
            float f3 = __uint_as_float(v.y & 0xffff0000u);
            acc0 = fmaf(ex, f0, acc0);
            acc1 = fmaf(ex, f1, acc1);
            acc2 = fmaf(ex, f2, acc2);
            acc3 = fmaf(ex, f3, acc3);
        }
    }
    float4 bv = ((const float4*)bias)[l];
    ushort4 o4;
    o4.x = f2bf(fmaxf(fmaf(acc0, rr, bv.x), 0.f));
    o4.y = f2bf(fmaxf(fmaf(acc1, rr, bv.y), 0.f));
    o4.z = f2bf(fmaxf(fmaf(acc2, rr, bv.z), 0.f));
    o4.w = f2bf(fmaxf(fmaf(acc3, rr, bv.w), 0.f));
    ((ushort4*)out1b)[(size_t)d * 64 + l] = o4;
}

// ---------- fused GAT layer 2 (H=1): one wave per dst, 4 dst/block ----------
__global__ __launch_bounds__(256) void fused_gat1(
    const int* __restrict__ off, const int* __restrict__ perm,
    const float* __restrict__ a_s, const float* __restrict__ a_d,
    const __hip_bfloat16* __restrict__ h2b, const float* __restrict__ bias,
    float* __restrict__ out2, int N) {
    __shared__ float2 alds[4][64];
    int w = threadIdx.x >> 6, l = threadIdx.x & 63;
    int d = blockIdx.x * 4 + w;
    if (d >= N) return;
    int lo = off[d], hi = off[d + 1];
    float add = a_d[d];
    float den = 0.f;
    for (int e = lo + l; e < hi; e += 64)
        den += expc(lrelu(a_s[perm[e]] + add));
    #pragma unroll
    for (int o = 32; o; o >>= 1) den += __shfl_xor(den, o);
    float rr = 1.f / (den + 1e-16f);
    const char* hb = (const char*)h2b;
    unsigned laneoff = (unsigned)l * 2u;
    float acc = 0.f;
    for (int base = lo; base < hi; base += 64) {
        int e = base + l;
        if (e < hi) {
            int s = perm[e];
            float ex = expc(lrelu(a_s[s] + add));
            alds[w][l] = make_float2(ex, __uint_as_float((unsigned)s * 128u));
        }
        int n = min(64, hi - base);
        #pragma unroll 4
        for (int i = 0; i < n; ++i) {
            float2 p = alds[w][i];
            unsigned voff = __float_as_uint(p.y) + laneoff;
            unsigned u = *(const unsigned short*)(hb + voff);
            acc = fmaf(p.x, __uint_as_float(u << 16), acc);
        }
    }
    out2[(size_t)d * 64 + l] = fmaxf(fmaf(acc, rr, bias[l]), 0.f);
}

// ---------- column sum over nodes ----------
__global__ void colsum_kernel(const float* __restrict__ x, float* __restrict__ g, int N) {
    __shared__ float part[4][64];
    int c = threadIdx.x & 63;
    int r = threadIdx.x >> 6;
    float acc = 0.f;
    for (long long n = (long long)blockIdx.x * 4 + r; n < N; n += (long long)gridDim.x * 4)
        acc += x[n * 64 + c];
    part[r][c] = acc;
    __syncthreads();
    if (r == 0) {
        float v = part[0][c] + part[1][c] + part[2][c] + part[3][c];
        atomAddF(&g[c], v);
    }
}

__global__ void final_kernel(const float* __restrict__ g, const float* __restrict__ Wv,
                             const float* __restrict__ bv, float* __restrict__ out, int N) {
    int lane = threadIdx.x;
    float v = (g[lane] / (float)N) * Wv[lane];
    #pragma unroll
    for (int off = 32; off; off >>= 1) v += __shfl_down(v, off);
    if (lane == 0) out[0] = v + bv[0];
}

extern "C" void kernel_launch(void* const* d_in, const int* in_sizes, int n_in,
                              void* d_out, int out_size, void* d_ws, size_t ws_size,
                              hipStream_t stream) {
    const float* nf   = (const float*)d_in[0];
    const float* act  = (const float*)d_in[1];
    const int*   ei   = (const int*)d_in[2];
    const float* Wemb = (const float*)d_in[3];
    const float* bemb = (const float*)d_in[4];
    const float* W1   = (const float*)d_in[5];
    const float* as1  = (const float*)d_in[6];
    const float* ad1  = (const float*)d_in[7];
    const float* b1   = (const float*)d_in[8];
    const float* W2   = (const float*)d_in[9];
    const float* as2  = (const float*)d_in[10];
    const float* ad2  = (const float*)d_in[11];
    const float* b2   = (const float*)d_in[12];
    const float* Wv   = (const float*)d_in[13];
    const float* bv   = (const float*)d_in[14];
    float* out = (float*)d_out;

    const int N = in_sizes[0] / FEAT;
    const int E = in_sizes[2] / 2;
    const int ET = E + N;
    const int* srcp = ei;
    const int* dstp = ei + E;
    const int NB = (N + 255) / 256;

    // ---- workspace layout ----
    float* ws = (float*)d_ws;
    float* x0 = ws;                                                  // N*64 f32
    __hip_bfloat16* h1b   = (__hip_bfloat16*)(x0 + (size_t)N * 64);  // N*256 bf16
    __hip_bfloat16* out1b = h1b + (size_t)N * 256;                   // N*256 bf16
    float* a_s  = (float*)(out1b + (size_t)N * 256);                 // N*4
    float* a_d  = a_s + (size_t)N * 4;                               // N*4
    __hip_bfloat16* h2b = (__hip_bfloat16*)(a_d + (size_t)N * 4);    // N*64 bf16
    float* out2 = (float*)(h2b + (size_t)N * 64);                    // N*64 f32
    float* g    = out2 + (size_t)N * 64;                             // 64
    __hip_bfloat16* w2t = (__hip_bfloat16*)(g + 64);                 // 64*256 bf16
    // CSR carved from x0 region (x0 dead after gemm1_scores)
    int* cnt  = (int*)x0;        // N
    int* off  = cnt + N;         // N+1
    int* cur  = off + N + 1;     // N
    int* perm = cur + N;         // ET
    int* bsum = perm + ET;       // NB
    int* bpre = bsum + NB;       // NB+1

    (void)ws_size; (void)n_in; (void)out_size;

    // ---- embedding ----
    emb_kernel<<<2048, 256, 0, stream>>>(nf, act, Wemb, bemb, x0, N);

    // ---- GAT layer 1: GEMM + scores (writes bf16 h1b) ----
    gemm1_scores<<<2048, 256, 0, stream>>>(x0, W1, as1, ad1, h1b, a_s, a_d, N);

    // ---- CSR build (x0 now dead) + W2 prep ----
    hipMemsetAsync(cnt, 0, (size_t)N * sizeof(int), stream);
    hipMemsetAsync(cur, 0, (size_t)N * sizeof(int), stream);
    hist_kernel<<<(ET + 255) / 256, 256, 0, stream>>>(dstp, cnt, E, ET);
    scan_blocks<<<NB, 256, 0, stream>>>(cnt, off, bsum, N);
    scan_tops<<<1, 256, 0, stream>>>(bsum, bpre, NB);
    scan_add<<<NB, 256, 0, stream>>>(bpre, off, N, NB);
    scatter_kernel<<<(ET + 255) / 256, 256, 0, stream>>>(srcp, dstp, off, cur, perm, E, ET);
    w2_prep<<<64, 256, 0, stream>>>(W2, w2t);

    // ---- GAT layer 1: fused softmax + aggregate + bias + relu (bf16 out) ----
    fused_gat4<<<(N + 3) / 4, 256, 0, stream>>>(off, perm, a_s, a_d, h1b, b1, out1b, N);

    // ---- GAT layer 2: MFMA GEMM + scores, then fused aggregate ----
    gemm2_mfma<<<(N + 63) / 64, 256, 0, stream>>>(out1b, w2t, as2, ad2, h2b, a_s, a_d, N);
    fused_gat1<<<(N + 3) / 4, 256, 0, stream>>>(off, perm, a_s, a_d, h2b, b2, out2, N);

    // ---- readout ----
    hipMemsetAsync(g, 0, 64 * sizeof(float), stream);
    colsum_kernel<<<512, 256, 0, stream>>>(out2, g, N);
    final_kernel<<<1, 64, 0, stream>>>(g, Wv, bv, out, N);
}

// Round 12
// 339.160 us; speedup vs baseline: 1.3651x; 1.0603x over previous
//
#include <hip/hip_runtime.h>
#include <hip/hip_bf16.h>
#include <math.h>

#define FEAT 96
#define ACTF 32

using frag8 = __attribute__((ext_vector_type(8))) short;   // 8 bf16 (4 VGPRs)
using f32x4 = __attribute__((ext_vector_type(4))) float;

__device__ __forceinline__ float lrelu(float x) { return x >= 0.f ? x : 0.2f * x; }
__device__ __forceinline__ void atomAddF(float* p, float v) {
    __hip_atomic_fetch_add(p, v, __ATOMIC_RELAXED, __HIP_MEMORY_SCOPE_AGENT);
}
__device__ __forceinline__ float expc(float x) { return __expf(fminf(x, 60.f)); }
__device__ __forceinline__ unsigned short f2bf(float f) {
    __hip_bfloat16 h = __float2bfloat16(f);
    return *(unsigned short*)&h;
}
__device__ __forceinline__ float bf2f(unsigned short u) {
    return __uint_as_float((unsigned)u << 16);
}

// ---------- X prep: Xh/Xl[N,128] = split-bf16 of [nf|act] ----------
__global__ __launch_bounds__(256) void xprep(
    const float* __restrict__ nf, const float* __restrict__ act,
    unsigned short* __restrict__ Xh, unsigned short* __restrict__ Xl, long long total) {
    long long i = (long long)blockIdx.x * 256 + threadIdx.x;
    if (i >= total) return;
    int n = (int)(i >> 7), k = (int)(i & 127);
    float v = (k < FEAT) ? nf[(size_t)n * FEAT + k] : act[(size_t)n * ACTF + (k - FEAT)];
    unsigned short h = f2bf(v);
    Xh[i] = h;
    Xl[i] = f2bf(v - bf2f(h));
}

// ---------- W1 prep: Wfused = Wemb@W1 (hi/lo bf16, transposed) + bfused ----------
__global__ void w1prep(const float* __restrict__ Wemb, const float* __restrict__ bemb,
                       const float* __restrict__ W1,
                       unsigned short* __restrict__ wfh, unsigned short* __restrict__ wfl,
                       float* __restrict__ bfused) {
    int k = blockIdx.x, c = threadIdx.x;
    if (k < 128) {
        float s = 0.f;
        for (int j = 0; j < 64; ++j) s = fmaf(Wemb[k * 64 + j], W1[j * 256 + c], s);
        unsigned short h = f2bf(s);
        wfh[(size_t)c * 128 + k] = h;
        wfl[(size_t)c * 128 + k] = f2bf(s - bf2f(h));
    } else {
        float s = 0.f;
        for (int j = 0; j < 64; ++j) s = fmaf(bemb[j], W1[j * 256 + c], s);
        bfused[c] = s;
    }
}

// ---------- GEMM1 via MFMA (split-bf16): h1b[N,256] = X@Wf + bfused; scores ----------
// Wave = 16 nodes x 256 ch. A: Xh/Xl rows; B: wfh/wfl [c][k].
// D lane mapping (verified m89): col=l&15, row=(l>>4)*4+reg.
__global__ __launch_bounds__(256) void gemm1_mfma(
    const unsigned short* __restrict__ Xh, const unsigned short* __restrict__ Xl,
    const unsigned short* __restrict__ wfh, const unsigned short* __restrict__ wfl,
    const float* __restrict__ bfused, const float* __restrict__ att_s,
    const float* __restrict__ att_d, __hip_bfloat16* __restrict__ h1b,
    float* __restrict__ a_s, float* __restrict__ a_d, int N) {
    int w = threadIdx.x >> 6, l = threadIdx.x & 63;
    int nb = (blockIdx.x * 4 + w) * 16;
    if (nb >= N) return;
    int r16 = l & 15, kg = l >> 4;
    int arow = min(nb + r16, N - 1);
    const short* ahp = (const short*)Xh + (size_t)arow * 128 + kg * 8;
    const short* alp = (const short*)Xl + (size_t)arow * 128 + kg * 8;
    frag8 ah[4], al[4];
    #pragma unroll
    for (int ks = 0; ks < 4; ++ks) {
        ah[ks] = *(const frag8*)(ahp + ks * 32);
        al[ks] = *(const frag8*)(alp + ks * 32);
    }
    f32x4 acc[16];
    #pragma unroll
    for (int ct = 0; ct < 16; ++ct) {
        acc[ct] = (f32x4){0.f, 0.f, 0.f, 0.f};
        const short* bhp = (const short*)wfh + (size_t)(ct * 16 + r16) * 128 + kg * 8;
        const short* blp = (const short*)wfl + (size_t)(ct * 16 + r16) * 128 + kg * 8;
        #pragma unroll
        for (int ks = 0; ks < 4; ++ks) {
            frag8 bh = *(const frag8*)(bhp + ks * 32);
            frag8 bl = *(const frag8*)(blp + ks * 32);
            acc[ct] = __builtin_amdgcn_mfma_f32_16x16x32_bf16(ah[ks], bh, acc[ct], 0, 0, 0);
            acc[ct] = __builtin_amdgcn_mfma_f32_16x16x32_bf16(al[ks], bh, acc[ct], 0, 0, 0);
            acc[ct] = __builtin_amdgcn_mfma_f32_16x16x32_bf16(ah[ks], bl, acc[ct], 0, 0, 0);
        }
    }
    float s_s[4] = {0.f, 0.f, 0.f, 0.f}, s_d[4] = {0.f, 0.f, 0.f, 0.f};
    #pragma unroll
    for (int ct = 0; ct < 16; ++ct) {
        int ch = ct * 16 + r16;
        float bias = bfused[ch];
        float aw = att_s[ch], dw = att_d[ch];
        #pragma unroll
        for (int r = 0; r < 4; ++r) {
            int node = nb + kg * 4 + r;
            float v = acc[ct][r] + bias;
            if (node < N) h1b[(size_t)node * 256 + ch] = __float2bfloat16(v);
            s_s[r] = fmaf(v, aw, s_s[r]);
            s_d[r] = fmaf(v, dw, s_d[r]);
        }
    }
    #pragma unroll
    for (int r = 0; r < 4; ++r) {
        #pragma unroll
        for (int o = 1; o < 16; o <<= 1) {
            s_s[r] += __shfl_xor(s_s[r], o);
            s_d[r] += __shfl_xor(s_d[r], o);
        }
        int node = nb + kg * 4 + r;
        if (r16 == 0 && node < N) {
            a_s[(size_t)node * 4] = 0.f;  // placeholder overwritten below (kept simple)
        }
    }
    // scores per head: a_s/a_d are [N,4]; head = ch>>6. Recompute reduction per head.
    // NOTE: above generic reduce gave the FULL 256-dot; but layer-1 needs per-head
    // (4 heads x 64ch) dots. Redo with head-split accumulators.
}

// The per-head variant (used): scores split by head (ct>>2 gives head, 4 ct per head).
__global__ __launch_bounds__(256) void gemm1_mfma_h(
    const unsigned short* __restrict__ Xh, const unsigned short* __restrict__ Xl,
    const unsigned short* __restrict__ wfh, const unsigned short* __restrict__ wfl,
    const float* __restrict__ bfused, const float* __restrict__ att_s,
    const float* __restrict__ att_d, __hip_bfloat16* __restrict__ h1b,
    float* __restrict__ a_s, float* __restrict__ a_d, int N) {
    int w = threadIdx.x >> 6, l = threadIdx.x & 63;
    int nb = (blockIdx.x * 4 + w) * 16;
    if (nb >= N) return;
    int r16 = l & 15, kg = l >> 4;
    int arow = min(nb + r16, N - 1);
    const short* ahp = (const short*)Xh + (size_t)arow * 128 + kg * 8;
    const short* alp = (const short*)Xl + (size_t)arow * 128 + kg * 8;
    frag8 ah[4], al[4];
    #pragma unroll
    for (int ks = 0; ks < 4; ++ks) {
        ah[ks] = *(const frag8*)(ahp + ks * 32);
        al[ks] = *(const frag8*)(alp + ks * 32);
    }
    f32x4 acc[16];
    #pragma unroll
    for (int ct = 0; ct < 16; ++ct) {
        acc[ct] = (f32x4){0.f, 0.f, 0.f, 0.f};
        const short* bhp = (const short*)wfh + (size_t)(ct * 16 + r16) * 128 + kg * 8;
        const short* blp = (const short*)wfl + (size_t)(ct * 16 + r16) * 128 + kg * 8;
        #pragma unroll
        for (int ks = 0; ks < 4; ++ks) {
            frag8 bh = *(const frag8*)(bhp + ks * 32);
            frag8 bl = *(const frag8*)(blp + ks * 32);
            acc[ct] = __builtin_amdgcn_mfma_f32_16x16x32_bf16(ah[ks], bh, acc[ct], 0, 0, 0);
            acc[ct] = __builtin_amdgcn_mfma_f32_16x16x32_bf16(al[ks], bh, acc[ct], 0, 0, 0);
            acc[ct] = __builtin_amdgcn_mfma_f32_16x16x32_bf16(ah[ks], bl, acc[ct], 0, 0, 0);
        }
    }
    // epilogue: store h1b; per-head score partials (head = ct>>2)
    float s_s[4][4], s_d[4][4];   // [head][r]
    #pragma unroll
    for (int hh = 0; hh < 4; ++hh)
        #pragma unroll
        for (int r = 0; r < 4; ++r) { s_s[hh][r] = 0.f; s_d[hh][r] = 0.f; }
    #pragma unroll
    for (int ct = 0; ct < 16; ++ct) {
        int ch = ct * 16 + r16;
        int hh = ct >> 2;
        float bias = bfused[ch];
        float aw = att_s[ch], dw = att_d[ch];
        #pragma unroll
        for (int r = 0; r < 4; ++r) {
            int node = nb + kg * 4 + r;
            float v = acc[ct][r] + bias;
            if (node < N) h1b[(size_t)node * 256 + ch] = __float2bfloat16(v);
            s_s[hh][r] = fmaf(v, aw, s_s[hh][r]);
            s_d[hh][r] = fmaf(v, dw, s_d[hh][r]);
        }
    }
    #pragma unroll
    for (int hh = 0; hh < 4; ++hh) {
        #pragma unroll
        for (int r = 0; r < 4; ++r) {
            float vs = s_s[hh][r], vd = s_d[hh][r];
            #pragma unroll
            for (int o = 1; o < 16; o <<= 1) {
                vs += __shfl_xor(vs, o);
                vd += __shfl_xor(vd, o);
            }
            int node = nb + kg * 4 + r;
            if (r16 == 0 && node < N) {
                a_s[(size_t)node * 4 + hh] = vs;
                a_d[(size_t)node * 4 + hh] = vd;
            }
        }
    }
}

// ---------- W2 -> bf16, transposed: w2t[c][k] = bf16(W2[k][c]) ----------
__global__ void w2_prep(const float* __restrict__ W2, __hip_bfloat16* __restrict__ w2t) {
    int i = blockIdx.x * 256 + threadIdx.x;   // 16384 total
    int k = i >> 6, c = i & 63;
    w2t[(size_t)c * 256 + k] = __float2bfloat16(W2[i]);
}

// ---------- GEMM2 via MFMA: h2b[N,64] = out1b[N,256] @ W2; scores fused ----------
__global__ __launch_bounds__(256) void gemm2_mfma(
    const __hip_bfloat16* __restrict__ out1b, const __hip_bfloat16* __restrict__ w2t,
    const float* __restrict__ att_s, const float* __restrict__ att_d,
    __hip_bfloat16* __restrict__ h2b, float* __restrict__ a_s, float* __restrict__ a_d,
    int N) {
    int w = threadIdx.x >> 6, l = threadIdx.x & 63;
    int nb = (blockIdx.x * 4 + w) * 16;
    if (nb >= N) return;
    int r16 = l & 15, kg = l >> 4;
    const short* A = (const short*)out1b;
    int arow = min(nb + r16, N - 1);
    const short* arp = A + (size_t)arow * 256 + kg * 8;
    frag8 a[8];
    #pragma unroll
    for (int ks = 0; ks < 8; ++ks) a[ks] = *(const frag8*)(arp + ks * 32);
    const short* B = (const short*)w2t;
    f32x4 acc[4];
    #pragma unroll
    for (int ct = 0; ct < 4; ++ct) {
        acc[ct] = (f32x4){0.f, 0.f, 0.f, 0.f};
        const short* brp = B + (size_t)(ct * 16 + r16) * 256 + kg * 8;
        #pragma unroll
        for (int ks = 0; ks < 8; ++ks) {
            frag8 b = *(const frag8*)(brp + ks * 32);
            acc[ct] = __builtin_amdgcn_mfma_f32_16x16x32_bf16(a[ks], b, acc[ct], 0, 0, 0);
        }
    }
    float s_s[4] = {0.f, 0.f, 0.f, 0.f}, s_d[4] = {0.f, 0.f, 0.f, 0.f};
    #pragma unroll
    for (int ct = 0; ct < 4; ++ct) {
        int ch = ct * 16 + r16;
        float aw = att_s[ch], dw = att_d[ch];
        #pragma unroll
        for (int r = 0; r < 4; ++r) {
            int node = nb + kg * 4 + r;
            float v = acc[ct][r];
            if (node < N) h2b[(size_t)node * 64 + ch] = __float2bfloat16(v);
            s_s[r] = fmaf(v, aw, s_s[r]);
            s_d[r] = fmaf(v, dw, s_d[r]);
        }
    }
    #pragma unroll
    for (int r = 0; r < 4; ++r) {
        #pragma unroll
        for (int o = 1; o < 16; o <<= 1) {
            s_s[r] += __shfl_xor(s_s[r], o);
            s_d[r] += __shfl_xor(s_d[r], o);
        }
        int node = nb + kg * 4 + r;
        if (r16 == 0 && node < N) { a_s[node] = s_s[r]; a_d[node] = s_d[r]; }
    }
}

// ---------- CSR build ----------
__global__ void hist_kernel(const int* __restrict__ dst, int* __restrict__ cnt, int E, int ET) {
    int e = blockIdx.x * blockDim.x + threadIdx.x;
    if (e >= ET) return;
    int d = (e < E) ? dst[e] : (e - E);
    atomicAdd(&cnt[d], 1);
}

__global__ __launch_bounds__(256) void scan_blocks(
    const int* __restrict__ cnt, int* __restrict__ off, int* __restrict__ bsum, int n) {
    int b = blockIdx.x, t = threadIdx.x;
    int i = b * 256 + t;
    int v = (i < n) ? cnt[i] : 0;
    int lane = t & 63, w = t >> 6;
    int x = v;
    #pragma unroll
    for (int o = 1; o < 64; o <<= 1) {
        int y = __shfl_up(x, o);
        if (lane >= o) x += y;
    }
    __shared__ int wtot[4];
    if (lane == 63) wtot[w] = x;
    __syncthreads();
    int add = 0;
    #pragma unroll
    for (int j = 0; j < 4; ++j) if (j < w) add += wtot[j];
    int incl = x + add;
    if (i < n) off[i] = incl - v;
    if (t == 255) bsum[b] = incl;
}

__global__ __launch_bounds__(256) void scan_tops(
    const int* __restrict__ bsum, int* __restrict__ bpre, int nb) {
    int t = threadIdx.x;
    int v = (t < nb) ? bsum[t] : 0;
    int lane = t & 63, w = t >> 6;
    int x = v;
    #pragma unroll
    for (int o = 1; o < 64; o <<= 1) {
        int y = __shfl_up(x, o);
        if (lane >= o) x += y;
    }
    __shared__ int wtot[4];
    if (lane == 63) wtot[w] = x;
    __syncthreads();
    int add = 0;
    #pragma unroll
    for (int j = 0; j < 4; ++j) if (j < w) add += wtot[j];
    if (t < nb) bpre[t] = x + add - v;
    if (t == 255) bpre[nb] = x + add;
}

__global__ __launch_bounds__(256) void scan_add(
    const int* __restrict__ bpre, int* __restrict__ off, int n, int nb) {
    int b = blockIdx.x, t = threadIdx.x;
    int i = b * 256 + t;
    if (i < n) off[i] += bpre[b];
    if (b == 0 && t == 0) off[n] = bpre[nb];
}

__global__ void scatter_kernel(const int* __restrict__ src, const int* __restrict__ dst,
                               const int* __restrict__ off, int* __restrict__ cur,
                               int* __restrict__ perm, int E, int ET) {
    int e = blockIdx.x * blockDim.x + threadIdx.x;
    if (e >= ET) return;
    int s = (e < E) ? src[e] : (e - E);
    int d = (e < E) ? dst[e] : (e - E);
    int r = atomicAdd(&cur[d], 1);
    perm[off[d] + r] = s;
}

// ---------- fused GAT layer 1 (H=4): one wave per dst, 4 dst/block ----------
__global__ __launch_bounds__(256) void fused_gat4(
    const int* __restrict__ off, const int* __restrict__ perm,
    const float* __restrict__ a_s, const float* __restrict__ a_d,
    const __hip_bfloat16* __restrict__ h1b, const float* __restrict__ bias,
    __hip_bfloat16* __restrict__ out1b, int N) {
    __shared__ float exls[4][64][4];
    __shared__ unsigned idxls[4][64];
    int w = threadIdx.x >> 6, l = threadIdx.x & 63;
    int d = blockIdx.x * 4 + w;
    if (d >= N) return;
    int lo = off[d], hi = off[d + 1];
    const float4* as4 = (const float4*)a_s;
    float4 ad = ((const float4*)a_d)[d];
    float dx = 0.f, dy = 0.f, dz = 0.f, dw = 0.f;
    for (int e = lo + l; e < hi; e += 64) {
        float4 a = as4[perm[e]];
        dx += expc(lrelu(a.x + ad.x));
        dy += expc(lrelu(a.y + ad.y));
        dz += expc(lrelu(a.z + ad.z));
        dw += expc(lrelu(a.w + ad.w));
    }
    #pragma unroll
    for (int o = 32; o; o >>= 1) {
        dx += __shfl_xor(dx, o); dy += __shfl_xor(dy, o);
        dz += __shfl_xor(dz, o); dw += __shfl_xor(dw, o);
    }
    int g = l >> 4;
    float rr = 1.f / ((g == 0 ? dx : g == 1 ? dy : g == 2 ? dz : dw) + 1e-16f);
    const char* hb = (const char*)h1b;
    unsigned laneoff = (unsigned)l * 8u;
    float acc0 = 0.f, acc1 = 0.f, acc2 = 0.f, acc3 = 0.f;
    for (int base = lo; base < hi; base += 64) {
        int e = base + l;
        if (e < hi) {
            int s = perm[e];
            float4 a = as4[s];
            exls[w][l][0] = expc(lrelu(a.x + ad.x));
            exls[w][l][1] = expc(lrelu(a.y + ad.y));
            exls[w][l][2] = expc(lrelu(a.z + ad.z));
            exls[w][l][3] = expc(lrelu(a.w + ad.w));
            idxls[w][l] = (unsigned)s * 512u;
        }
        int n = min(64, hi - base);
        #pragma unroll 4
        for (int i = 0; i < n; ++i) {
            float ex = exls[w][i][g];
            unsigned voff = idxls[w][i] + laneoff;
            uint2 v = *(const uint2*)(hb + voff);
            float f0 = __uint_as_float(v.x << 16);
            float f1 = __uint_as_float(v.x & 0xffff0000u);
            float f2 = __uint_as_float(v.y << 16);
            float f3 = __uint_as_float(v.y & 0xffff0000u);
            acc0 = fmaf(ex, f0, acc0);
            acc1 = fmaf(ex, f1, acc1);
            acc2 = fmaf(ex, f2, acc2);
            acc3 = fmaf(ex, f3, acc3);
        }
    }
    float4 bv = ((const float4*)bias)[l];
    ushort4 o4;
    o4.x = f2bf(fmaxf(fmaf(acc0, rr, bv.x), 0.f));
    o4.y = f2bf(fmaxf(fmaf(acc1, rr, bv.y), 0.f));
    o4.z = f2bf(fmaxf(fmaf(acc2, rr, bv.z), 0.f));
    o4.w = f2bf(fmaxf(fmaf(acc3, rr, bv.w), 0.f));
    ((ushort4*)out1b)[(size_t)d * 64 + l] = o4;
}

// ---------- fused GAT layer 2 (H=1): one wave per dst, 4 dst/block ----------
__global__ __launch_bounds__(256) void fused_gat1(
    const int* __restrict__ off, const int* __restrict__ perm,
    const float* __restrict__ a_s, const float* __restrict__ a_d,
    const __hip_bfloat16* __restrict__ h2b, const float* __restrict__ bias,
    float* __restrict__ out2, int N) {
    __shared__ float2 alds[4][64];
    int w = threadIdx.x >> 6, l = threadIdx.x & 63;
    int d = blockIdx.x * 4 + w;
    if (d >= N) return;
    int lo = off[d], hi = off[d + 1];
    float add = a_d[d];
    float den = 0.f;
    for (int e = lo + l; e < hi; e += 64)
        den += expc(lrelu(a_s[perm[e]] + add));
    #pragma unroll
    for (int o = 32; o; o >>= 1) den += __shfl_xor(den, o);
    float rr = 1.f / (den + 1e-16f);
    const char* hb = (const char*)h2b;
    unsigned laneoff = (unsigned)l * 2u;
    float acc = 0.f;
    for (int base = lo; base < hi; base += 64) {
        int e = base + l;
        if (e < hi) {
            int s = perm[e];
            float ex = expc(lrelu(a_s[s] + add));
            alds[w][l] = make_float2(ex, __uint_as_float((unsigned)s * 128u));
        }
        int n = min(64, hi - base);
        #pragma unroll 4
        for (int i = 0; i < n; ++i) {
            float2 p = alds[w][i];
            unsigned voff = __float_as_uint(p.y) + laneoff;
            unsigned u = *(const unsigned short*)(hb + voff);
            acc = fmaf(p.x, __uint_as_float(u << 16), acc);
        }
    }
    out2[(size_t)d * 64 + l] = fmaxf(fmaf(acc, rr, bias[l]), 0.f);
}

// ---------- column sum over nodes ----------
__global__ void colsum_kernel(const float* __restrict__ x, float* __restrict__ g, int N) {
    __shared__ float part[4][64];
    int c = threadIdx.x & 63;
    int r = threadIdx.x >> 6;
    float acc = 0.f;
    for (long long n = (long long)blockIdx.x * 4 + r; n < N; n += (long long)gridDim.x * 4)
        acc += x[n * 64 + c];
    part[r][c] = acc;
    __syncthreads();
    if (r == 0) {
        float v = part[0][c] + part[1][c] + part[2][c] + part[3][c];
        atomAddF(&g[c], v);
    }
}

__global__ void final_kernel(const float* __restrict__ g, const float* __restrict__ Wv,
                             const float* __restrict__ bv, float* __restrict__ out, int N) {
    int lane = threadIdx.x;
    float v = (g[lane] / (float)N) * Wv[lane];
    #pragma unroll
    for (int off = 32; off; off >>= 1) v += __shfl_down(v, off);
    if (lane == 0) out[0] = v + bv[0];
}

extern "C" void kernel_launch(void* const* d_in, const int* in_sizes, int n_in,
                              void* d_out, int out_size, void* d_ws, size_t ws_size,
                              hipStream_t stream) {
    const float* nf   = (const float*)d_in[0];
    const float* act  = (const float*)d_in[1];
    const int*   ei   = (const int*)d_in[2];
    const float* Wemb = (const float*)d_in[3];
    const float* bemb = (const float*)d_in[4];
    const float* W1   = (const float*)d_in[5];
    const float* as1  = (const float*)d_in[6];
    const float* ad1  = (const float*)d_in[7];
    const float* b1   = (const float*)d_in[8];
    const float* W2   = (const float*)d_in[9];
    const float* as2  = (const float*)d_in[10];
    const float* ad2  = (const float*)d_in[11];
    const float* b2   = (const float*)d_in[12];
    const float* Wv   = (const float*)d_in[13];
    const float* bv   = (const float*)d_in[14];
    float* out = (float*)d_out;

    const int N = in_sizes[0] / FEAT;
    const int E = in_sizes[2] / 2;
    const int ET = E + N;
    const int* srcp = ei;
    const int* dstp = ei + E;
    const int NB = (N + 255) / 256;

    // ---- workspace layout ----
    char* ws = (char*)d_ws;
    unsigned short* Xh = (unsigned short*)ws;                         // N*128 bf16
    unsigned short* Xl = Xh + (size_t)N * 128;                        // N*128 bf16
    __hip_bfloat16* h1b   = (__hip_bfloat16*)(Xl + (size_t)N * 128);  // N*256 bf16
    __hip_bfloat16* out1b = h1b + (size_t)N * 256;                    // N*256 bf16
    float* a_s  = (float*)(out1b + (size_t)N * 256);                  // N*4 f32
    float* a_d  = a_s + (size_t)N * 4;                                // N*4 f32
    __hip_bfloat16* h2b = (__hip_bfloat16*)(a_d + (size_t)N * 4);     // N*64 bf16
    float* out2 = (float*)(h2b + (size_t)N * 64);                     // N*64 f32
    float* g    = out2 + (size_t)N * 64;                              // 64
    __hip_bfloat16* w2t = (__hip_bfloat16*)(g + 64);                  // 64*256 bf16
    unsigned short* wfh = (unsigned short*)(w2t + 64 * 256);          // 256*128
    unsigned short* wfl = wfh + 256 * 128;                            // 256*128
    float* bfused = (float*)(wfl + 256 * 128);                        // 256 f32
    // CSR carved from Xh/Xl region (dead after gemm1_mfma_h)
    int* cnt  = (int*)Xh;        // N
    int* off  = cnt + N;         // N+1
    int* cur  = off + N + 1;     // N
    int* perm = cur + N;         // ET
    int* bsum = perm + ET;       // NB
    int* bpre = bsum + NB;       // NB+1

    (void)ws_size; (void)n_in; (void)out_size;

    // ---- X prep (split-bf16) + fused-weight prep ----
    long long xtot = (long long)N * 128;
    xprep<<<(int)((xtot + 255) / 256), 256, 0, stream>>>(nf, act, Xh, Xl, xtot);
    w1prep<<<129, 256, 0, stream>>>(Wemb, bemb, W1, wfh, wfl, bfused);
    w2_prep<<<64, 256, 0, stream>>>(W2, w2t);

    // ---- GAT layer 1 GEMM (MFMA, fused emb): h1b + scores ----
    gemm1_mfma_h<<<(N + 63) / 64, 256, 0, stream>>>(Xh, Xl, wfh, wfl, bfused,
                                                    as1, ad1, h1b, a_s, a_d, N);

    // ---- CSR build (Xh/Xl now dead) ----
    hipMemsetAsync(cnt, 0, (size_t)N * sizeof(int), stream);
    hipMemsetAsync(cur, 0, (size_t)N * sizeof(int), stream);
    hist_kernel<<<(ET + 255) / 256, 256, 0, stream>>>(dstp, cnt, E, ET);
    scan_blocks<<<NB, 256, 0, stream>>>(cnt, off, bsum, N);
    scan_tops<<<1, 256, 0, stream>>>(bsum, bpre, NB);
    scan_add<<<NB, 256, 0, stream>>>(bpre, off, N, NB);
    scatter_kernel<<<(ET + 255) / 256, 256, 0, stream>>>(srcp, dstp, off, cur, perm, E, ET);

    // ---- GAT layer 1: fused softmax + aggregate + bias + relu (bf16 out) ----
    fused_gat4<<<(N + 3) / 4, 256, 0, stream>>>(off, perm, a_s, a_d, h1b, b1, out1b, N);

    // ---- GAT layer 2: MFMA GEMM + scores, then fused aggregate ----
    gemm2_mfma<<<(N + 63) / 64, 256, 0, stream>>>(out1b, w2t, as2, ad2, h2b, a_s, a_d, N);
    fused_gat1<<<(N + 3) / 4, 256, 0, stream>>>(off, perm, a_s, a_d, h2b, b2, out2, N);

    // ---- readout ----
    hipMemsetAsync(g, 0, 64 * sizeof(float), stream);
    colsum_kernel<<<512, 256, 0, stream>>>(out2, g, N);
    final_kernel<<<1, 64, 0, stream>>>(g, Wv, bv, out, N);
}

// Round 13
// 293.797 us; speedup vs baseline: 1.5759x; 1.1544x over previous
//
#include <hip/hip_runtime.h>
#include <hip/hip_bf16.h>
#include <math.h>

#define FEAT 96
#define ACTF 32

using frag8 = __attribute__((ext_vector_type(8))) short;   // 8 bf16 (4 VGPRs)
using f32x4 = __attribute__((ext_vector_type(4))) float;

__device__ __forceinline__ float lrelu(float x) { return x >= 0.f ? x : 0.2f * x; }
__device__ __forceinline__ void atomAddF(float* p, float v) {
    __hip_atomic_fetch_add(p, v, __ATOMIC_RELAXED, __HIP_MEMORY_SCOPE_AGENT);
}
__device__ __forceinline__ float expc(float x) { return __expf(fminf(x, 60.f)); }
__device__ __forceinline__ unsigned short f2bf(float f) {
    __hip_bfloat16 h = __float2bfloat16(f);
    return *(unsigned short*)&h;
}
__device__ __forceinline__ float bf2f(unsigned short u) {
    return __uint_as_float((unsigned)u << 16);
}

// ---------- X prep: Xh/Xl[N,128] = split-bf16 of [nf|act] ----------
__global__ __launch_bounds__(256) void xprep(
    const float* __restrict__ nf, const float* __restrict__ act,
    unsigned short* __restrict__ Xh, unsigned short* __restrict__ Xl, long long total) {
    long long i = (long long)blockIdx.x * 256 + threadIdx.x;
    if (i >= total) return;
    int n = (int)(i >> 7), k = (int)(i & 127);
    float v = (k < FEAT) ? nf[(size_t)n * FEAT + k] : act[(size_t)n * ACTF + (k - FEAT)];
    unsigned short h = f2bf(v);
    Xh[i] = h;
    Xl[i] = f2bf(v - bf2f(h));
}

// ---------- W1 prep: Wfused = Wemb@W1 (hi/lo bf16, transposed) + bfused ----------
__global__ void w1prep(const float* __restrict__ Wemb, const float* __restrict__ bemb,
                       const float* __restrict__ W1,
                       unsigned short* __restrict__ wfh, unsigned short* __restrict__ wfl,
                       float* __restrict__ bfused) {
    int k = blockIdx.x, c = threadIdx.x;
    if (k < 128) {
        float s = 0.f;
        for (int j = 0; j < 64; ++j) s = fmaf(Wemb[k * 64 + j], W1[j * 256 + c], s);
        unsigned short h = f2bf(s);
        wfh[(size_t)c * 128 + k] = h;
        wfl[(size_t)c * 128 + k] = f2bf(s - bf2f(h));
    } else {
        float s = 0.f;
        for (int j = 0; j < 64; ++j) s = fmaf(bemb[j], W1[j * 256 + c], s);
        bfused[c] = s;
    }
}

// ---------- GEMM1 via MFMA (split-bf16, B-in-register, ct split by wave) ----------
// Wave w owns col-tiles 4w..4w+3 == head w (channels 64w..64w+63).
// B fragments held in VGPRs across a grid-stride tile loop; per tile only
// 16 streaming A-loads + 48 MFMA + epilogue (store h1b, per-head scores).
__global__ __launch_bounds__(256, 2) void gemm1_mfma_w(
    const unsigned short* __restrict__ Xh, const unsigned short* __restrict__ Xl,
    const unsigned short* __restrict__ wfh, const unsigned short* __restrict__ wfl,
    const float* __restrict__ bfused, const float* __restrict__ att_s,
    const float* __restrict__ att_d, __hip_bfloat16* __restrict__ h1b,
    float* __restrict__ a_s, float* __restrict__ a_d, int N) {
    int w = threadIdx.x >> 6, l = threadIdx.x & 63;
    int r16 = l & 15, kg = l >> 4;
    // B fragments for this wave's 4 col-tiles (one-time load, lives in VGPRs)
    frag8 bh[4][4], bl[4][4];
    #pragma unroll
    for (int c = 0; c < 4; ++c) {
        int ct = w * 4 + c;
        const short* bhp = (const short*)wfh + (size_t)(ct * 16 + r16) * 128 + kg * 8;
        const short* blp = (const short*)wfl + (size_t)(ct * 16 + r16) * 128 + kg * 8;
        #pragma unroll
        for (int ks = 0; ks < 4; ++ks) {
            bh[c][ks] = *(const frag8*)(bhp + ks * 32);
            bl[c][ks] = *(const frag8*)(blp + ks * 32);
        }
    }
    float biasv[4], awv[4], dwv[4];
    #pragma unroll
    for (int c = 0; c < 4; ++c) {
        int ch = w * 64 + c * 16 + r16;
        biasv[c] = bfused[ch];
        awv[c] = att_s[ch];
        dwv[c] = att_d[ch];
    }
    int ntiles = (N + 15) >> 4;
    for (int tile = blockIdx.x; tile < ntiles; tile += gridDim.x) {
        int nb = tile * 16;
        int arow = nb + r16; if (arow >= N) arow = N - 1;
        const short* ahp = (const short*)Xh + (size_t)arow * 128 + kg * 8;
        const short* alp = (const short*)Xl + (size_t)arow * 128 + kg * 8;
        frag8 ah[4], al[4];
        #pragma unroll
        for (int ks = 0; ks < 4; ++ks) {
            ah[ks] = *(const frag8*)(ahp + ks * 32);
            al[ks] = *(const frag8*)(alp + ks * 32);
        }
        float s_s[4] = {0.f, 0.f, 0.f, 0.f}, s_d[4] = {0.f, 0.f, 0.f, 0.f};
        #pragma unroll
        for (int c = 0; c < 4; ++c) {
            f32x4 acc = (f32x4){0.f, 0.f, 0.f, 0.f};
            #pragma unroll
            for (int ks = 0; ks < 4; ++ks) {
                acc = __builtin_amdgcn_mfma_f32_16x16x32_bf16(ah[ks], bh[c][ks], acc, 0, 0, 0);
                acc = __builtin_amdgcn_mfma_f32_16x16x32_bf16(al[ks], bh[c][ks], acc, 0, 0, 0);
                acc = __builtin_amdgcn_mfma_f32_16x16x32_bf16(ah[ks], bl[c][ks], acc, 0, 0, 0);
            }
            int ch = w * 64 + c * 16 + r16;
            #pragma unroll
            for (int r = 0; r < 4; ++r) {
                int node = nb + kg * 4 + r;
                float v = acc[r] + biasv[c];
                if (node < N) h1b[(size_t)node * 256 + ch] = __float2bfloat16(v);
                s_s[r] = fmaf(v, awv[c], s_s[r]);
                s_d[r] = fmaf(v, dwv[c], s_d[r]);
            }
        }
        #pragma unroll
        for (int r = 0; r < 4; ++r) {
            float vs = s_s[r], vd = s_d[r];
            #pragma unroll
            for (int o = 1; o < 16; o <<= 1) {
                vs += __shfl_xor(vs, o);
                vd += __shfl_xor(vd, o);
            }
            int node = nb + kg * 4 + r;
            if (r16 == 0 && node < N) {
                a_s[(size_t)node * 4 + w] = vs;
                a_d[(size_t)node * 4 + w] = vd;
            }
        }
    }
}

// ---------- W2 -> bf16, transposed: w2t[c][k] = bf16(W2[k][c]) ----------
__global__ void w2_prep(const float* __restrict__ W2, __hip_bfloat16* __restrict__ w2t) {
    int i = blockIdx.x * 256 + threadIdx.x;   // 16384 total
    int k = i >> 6, c = i & 63;
    w2t[(size_t)c * 256 + k] = __float2bfloat16(W2[i]);
}

// ---------- GEMM2 via MFMA: h2b[N,64] = out1b[N,256] @ W2; scores fused ----------
__global__ __launch_bounds__(256) void gemm2_mfma(
    const __hip_bfloat16* __restrict__ out1b, const __hip_bfloat16* __restrict__ w2t,
    const float* __restrict__ att_s, const float* __restrict__ att_d,
    __hip_bfloat16* __restrict__ h2b, float* __restrict__ a_s, float* __restrict__ a_d,
    int N) {
    int w = threadIdx.x >> 6, l = threadIdx.x & 63;
    int nb = (blockIdx.x * 4 + w) * 16;
    if (nb >= N) return;
    int r16 = l & 15, kg = l >> 4;
    const short* A = (const short*)out1b;
    int arow = min(nb + r16, N - 1);
    const short* arp = A + (size_t)arow * 256 + kg * 8;
    frag8 a[8];
    #pragma unroll
    for (int ks = 0; ks < 8; ++ks) a[ks] = *(const frag8*)(arp + ks * 32);
    const short* B = (const short*)w2t;
    f32x4 acc[4];
    #pragma unroll
    for (int ct = 0; ct < 4; ++ct) {
        acc[ct] = (f32x4){0.f, 0.f, 0.f, 0.f};
        const short* brp = B + (size_t)(ct * 16 + r16) * 256 + kg * 8;
        #pragma unroll
        for (int ks = 0; ks < 8; ++ks) {
            frag8 b = *(const frag8*)(brp + ks * 32);
            acc[ct] = __builtin_amdgcn_mfma_f32_16x16x32_bf16(a[ks], b, acc[ct], 0, 0, 0);
        }
    }
    float s_s[4] = {0.f, 0.f, 0.f, 0.f}, s_d[4] = {0.f, 0.f, 0.f, 0.f};
    #pragma unroll
    for (int ct = 0; ct < 4; ++ct) {
        int ch = ct * 16 + r16;
        float aw = att_s[ch], dw = att_d[ch];
        #pragma unroll
        for (int r = 0; r < 4; ++r) {
            int node = nb + kg * 4 + r;
            float v = acc[ct][r];
            if (node < N) h2b[(size_t)node * 64 + ch] = __float2bfloat16(v);
            s_s[r] = fmaf(v, aw, s_s[r]);
            s_d[r] = fmaf(v, dw, s_d[r]);
        }
    }
    #pragma unroll
    for (int r = 0; r < 4; ++r) {
        #pragma unroll
        for (int o = 1; o < 16; o <<= 1) {
            s_s[r] += __shfl_xor(s_s[r], o);
            s_d[r] += __shfl_xor(s_d[r], o);
        }
        int node = nb + kg * 4 + r;
        if (r16 == 0 && node < N) { a_s[node] = s_s[r]; a_d[node] = s_d[r]; }
    }
}

// ---------- CSR build ----------
__global__ void hist_kernel(const int* __restrict__ dst, int* __restrict__ cnt, int E, int ET) {
    int e = blockIdx.x * blockDim.x + threadIdx.x;
    if (e >= ET) return;
    int d = (e < E) ? dst[e] : (e - E);
    atomicAdd(&cnt[d], 1);
}

__global__ __launch_bounds__(256) void scan_blocks(
    const int* __restrict__ cnt, int* __restrict__ off, int* __restrict__ bsum, int n) {
    int b = blockIdx.x, t = threadIdx.x;
    int i = b * 256 + t;
    int v = (i < n) ? cnt[i] : 0;
    int lane = t & 63, w = t >> 6;
    int x = v;
    #pragma unroll
    for (int o = 1; o < 64; o <<= 1) {
        int y = __shfl_up(x, o);
        if (lane >= o) x += y;
    }
    __shared__ int wtot[4];
    if (lane == 63) wtot[w] = x;
    __syncthreads();
    int add = 0;
    #pragma unroll
    for (int j = 0; j < 4; ++j) if (j < w) add += wtot[j];
    int incl = x + add;
    if (i < n) off[i] = incl - v;
    if (t == 255) bsum[b] = incl;
}

__global__ __launch_bounds__(256) void scan_tops(
    const int* __restrict__ bsum, int* __restrict__ bpre, int nb) {
    int t = threadIdx.x;
    int v = (t < nb) ? bsum[t] : 0;
    int lane = t & 63, w = t >> 6;
    int x = v;
    #pragma unroll
    for (int o = 1; o < 64; o <<= 1) {
        int y = __shfl_up(x, o);
        if (lane >= o) x += y;
    }
    __shared__ int wtot[4];
    if (lane == 63) wtot[w] = x;
    __syncthreads();
    int add = 0;
    #pragma unroll
    for (int j = 0; j < 4; ++j) if (j < w) add += wtot[j];
    if (t < nb) bpre[t] = x + add - v;
    if (t == 255) bpre[nb] = x + add;
}

__global__ __launch_bounds__(256) void scan_add(
    const int* __restrict__ bpre, int* __restrict__ off, int n, int nb) {
    int b = blockIdx.x, t = threadIdx.x;
    int i = b * 256 + t;
    if (i < n) off[i] += bpre[b];
    if (b == 0 && t == 0) off[n] = bpre[nb];
}

__global__ void scatter_kernel(const int* __restrict__ src, const int* __restrict__ dst,
                               const int* __restrict__ off, int* __restrict__ cur,
                               int* __restrict__ perm, int E, int ET) {
    int e = blockIdx.x * blockDim.x + threadIdx.x;
    if (e >= ET) return;
    int s = (e < E) ? src[e] : (e - E);
    int d = (e < E) ? dst[e] : (e - E);
    int r = atomicAdd(&cur[d], 1);
    perm[off[d] + r] = s;
}

// ---------- fused GAT layer 1 (H=4): one wave per dst, 4 dst/block ----------
__global__ __launch_bounds__(256) void fused_gat4(
    const int* __restrict__ off, const int* __restrict__ perm,
    const float* __restrict__ a_s, const float* __restrict__ a_d,
    const __hip_bfloat16* __restrict__ h1b, const float* __restrict__ bias,
    __hip_bfloat16* __restrict__ out1b, int N) {
    __shared__ float exls[4][64][4];
    __shared__ unsigned idxls[4][64];
    int w = threadIdx.x >> 6, l = threadIdx.x & 63;
    int d = blockIdx.x * 4 + w;
    if (d >= N) return;
    int lo = off[d], hi = off[d + 1];
    const float4* as4 = (const float4*)a_s;
    float4 ad = ((const float4*)a_d)[d];
    float dx = 0.f, dy = 0.f, dz = 0.f, dw = 0.f;
    for (int e = lo + l; e < hi; e += 64) {
        float4 a = as4[perm[e]];
        dx += expc(lrelu(a.x + ad.x));
        dy += expc(lrelu(a.y + ad.y));
        dz += expc(lrelu(a.z + ad.z));
        dw += expc(lrelu(a.w + ad.w));
    }
    #pragma unroll
    for (int o = 32; o; o >>= 1) {
        dx += __shfl_xor(dx, o); dy += __shfl_xor(dy, o);
        dz += __shfl_xor(dz, o); dw += __shfl_xor(dw, o);
    }
    int g = l >> 4;
    float rr = 1.f / ((g == 0 ? dx : g == 1 ? dy : g == 2 ? dz : dw) + 1e-16f);
    const char* hb = (const char*)h1b;
    unsigned laneoff = (unsigned)l * 8u;
    float acc0 = 0.f, acc1 = 0.f, acc2 = 0.f, acc3 = 0.f;
    for (int base = lo; base < hi; base += 64) {
        int e = base + l;
        if (e < hi) {
            int s = perm[e];
            float4 a = as4[s];
            exls[w][l][0] = expc(lrelu(a.x + ad.x));
            exls[w][l][1] = expc(lrelu(a.y + ad.y));
            exls[w][l][2] = expc(lrelu(a.z + ad.z));
            exls[w][l][3] = expc(lrelu(a.w + ad.w));
            idxls[w][l] = (unsigned)s * 512u;
        }
        int n = min(64, hi - base);
        #pragma unroll 4
        for (int i = 0; i < n; ++i) {
            float ex = exls[w][i][g];
            unsigned voff = idxls[w][i] + laneoff;
            uint2 v = *(const uint2*)(hb + voff);
            float f0 = __uint_as_float(v.x << 16);
            float f1 = __uint_as_float(v.x & 0xffff0000u);
            float f2 = __uint_as_float(v.y << 16);
            float f3 = __uint_as_float(v.y & 0xffff0000u);
            acc0 = fmaf(ex, f0, acc0);
            acc1 = fmaf(ex, f1, acc1);
            acc2 = fmaf(ex, f2, acc2);
            acc3 = fmaf(ex, f3, acc3);
        }
    }
    float4 bv = ((const float4*)bias)[l];
    ushort4 o4;
    o4.x = f2bf(fmaxf(fmaf(acc0, rr, bv.x), 0.f));
    o4.y = f2bf(fmaxf(fmaf(acc1, rr, bv.y), 0.f));
    o4.z = f2bf(fmaxf(fmaf(acc2, rr, bv.z), 0.f));
    o4.w = f2bf(fmaxf(fmaf(acc3, rr, bv.w), 0.f));
    ((ushort4*)out1b)[(size_t)d * 64 + l] = o4;
}

// ---------- fused GAT layer 2 (H=1): one wave per dst, 4 dst/block ----------
__global__ __launch_bounds__(256) void fused_gat1(
    const int* __restrict__ off, const int* __restrict__ perm,
    const float* __restrict__ a_s, const float* __restrict__ a_d,
    const __hip_bfloat16* __restrict__ h2b, const float* __restrict__ bias,
    float* __restrict__ out2, int N) {
    __shared__ float2 alds[4][64];
    int w = threadIdx.x >> 6, l = threadIdx.x & 63;
    int d = blockIdx.x * 4 + w;
    if (d >= N) return;
    int lo = off[d], hi = off[d + 1];
    float add = a_d[d];
    float den = 0.f;
    for (int e = lo + l; e < hi; e += 64)
        den += expc(lrelu(a_s[perm[e]] + add));
    #pragma unroll
    for (int o = 32; o; o >>= 1) den += __shfl_xor(den, o);
    float rr = 1.f / (den + 1e-16f);
    const char* hb = (const char*)h2b;
    unsigned laneoff = (unsigned)l * 2u;
    float acc = 0.f;
    for (int base = lo; base < hi; base += 64) {
        int e = base + l;
        if (e < hi) {
            int s = perm[e];
            float ex = expc(lrelu(a_s[s] + add));
            alds[w][l] = make_float2(ex, __uint_as_float((unsigned)s * 128u));
        }
        int n = min(64, hi - base);
        #pragma unroll 4
        for (int i = 0; i < n; ++i) {
            float2 p = alds[w][i];
            unsigned voff = __float_as_uint(p.y) + laneoff;
            unsigned u = *(const unsigned short*)(hb + voff);
            acc = fmaf(p.x, __uint_as_float(u << 16), acc);
        }
    }
    out2[(size_t)d * 64 + l] = fmaxf(fmaf(acc, rr, bias[l]), 0.f);
}

// ---------- column sum over nodes ----------
__global__ void colsum_kernel(const float* __restrict__ x, float* __restrict__ g, int N) {
    __shared__ float part[4][64];
    int c = threadIdx.x & 63;
    int r = threadIdx.x >> 6;
    float acc = 0.f;
    for (long long n = (long long)blockIdx.x * 4 + r; n < N; n += (long long)gridDim.x * 4)
        acc += x[n * 64 + c];
    part[r][c] = acc;
    __syncthreads();
    if (r == 0) {
        float v = part[0][c] + part[1][c] + part[2][c] + part[3][c];
        atomAddF(&g[c], v);
    }
}

__global__ void final_kernel(const float* __restrict__ g, const float* __restrict__ Wv,
                             const float* __restrict__ bv, float* __restrict__ out, int N) {
    int lane = threadIdx.x;
    float v = (g[lane] / (float)N) * Wv[lane];
    #pragma unroll
    for (int off = 32; off; off >>= 1) v += __shfl_down(v, off);
    if (lane == 0) out[0] = v + bv[0];
}

extern "C" void kernel_launch(void* const* d_in, const int* in_sizes, int n_in,
                              void* d_out, int out_size, void* d_ws, size_t ws_size,
                              hipStream_t stream) {
    const float* nf   = (const float*)d_in[0];
    const float* act  = (const float*)d_in[1];
    const int*   ei   = (const int*)d_in[2];
    const float* Wemb = (const float*)d_in[3];
    const float* bemb = (const float*)d_in[4];
    const float* W1   = (const float*)d_in[5];
    const float* as1  = (const float*)d_in[6];
    const float* ad1  = (const float*)d_in[7];
    const float* b1   = (const float*)d_in[8];
    const float* W2   = (const float*)d_in[9];
    const float* as2  = (const float*)d_in[10];
    const float* ad2  = (const float*)d_in[11];
    const float* b2   = (const float*)d_in[12];
    const float* Wv   = (const float*)d_in[13];
    const float* bv   = (const float*)d_in[14];
    float* out = (float*)d_out;

    const int N = in_sizes[0] / FEAT;
    const int E = in_sizes[2] / 2;
    const int ET = E + N;
    const int* srcp = ei;
    const int* dstp = ei + E;
    const int NB = (N + 255) / 256;

    // ---- workspace layout ----
    char* ws = (char*)d_ws;
    unsigned short* Xh = (unsigned short*)ws;                         // N*128 bf16
    unsigned short* Xl = Xh + (size_t)N * 128;                        // N*128 bf16
    __hip_bfloat16* h1b   = (__hip_bfloat16*)(Xl + (size_t)N * 128);  // N*256 bf16
    __hip_bfloat16* out1b = h1b + (size_t)N * 256;                    // N*256 bf16
    float* a_s  = (float*)(out1b + (size_t)N * 256);                  // N*4 f32
    float* a_d  = a_s + (size_t)N * 4;                                // N*4 f32
    __hip_bfloat16* h2b = (__hip_bfloat16*)(a_d + (size_t)N * 4);     // N*64 bf16
    float* out2 = (float*)(h2b + (size_t)N * 64);                     // N*64 f32
    float* g    = out2 + (size_t)N * 64;                              // 64
    __hip_bfloat16* w2t = (__hip_bfloat16*)(g + 64);                  // 64*256 bf16
    unsigned short* wfh = (unsigned short*)(w2t + 64 * 256);          // 256*128
    unsigned short* wfl = wfh + 256 * 128;                            // 256*128
    float* bfused = (float*)(wfl + 256 * 128);                        // 256 f32
    // CSR carved from Xh/Xl region (dead after gemm1_mfma_w)
    int* cnt  = (int*)Xh;        // N
    int* off  = cnt + N;         // N+1
    int* cur  = off + N + 1;     // N
    int* perm = cur + N;         // ET
    int* bsum = perm + ET;       // NB
    int* bpre = bsum + NB;       // NB+1

    (void)ws_size; (void)n_in; (void)out_size;

    // ---- X prep (split-bf16) + fused-weight prep ----
    long long xtot = (long long)N * 128;
    xprep<<<(int)((xtot + 255) / 256), 256, 0, stream>>>(nf, act, Xh, Xl, xtot);
    w1prep<<<129, 256, 0, stream>>>(Wemb, bemb, W1, wfh, wfl, bfused);
    w2_prep<<<64, 256, 0, stream>>>(W2, w2t);

    // ---- GAT layer 1 GEMM (MFMA, fused emb, B-in-register): h1b + scores ----
    gemm1_mfma_w<<<1024, 256, 0, stream>>>(Xh, Xl, wfh, wfl, bfused,
                                           as1, ad1, h1b, a_s, a_d, N);

    // ---- CSR build (Xh/Xl now dead) ----
    hipMemsetAsync(cnt, 0, (size_t)N * sizeof(int), stream);
    hipMemsetAsync(cur, 0, (size_t)N * sizeof(int), stream);
    hist_kernel<<<(ET + 255) / 256, 256, 0, stream>>>(dstp, cnt, E, ET);
    scan_blocks<<<NB, 256, 0, stream>>>(cnt, off, bsum, N);
    scan_tops<<<1, 256, 0, stream>>>(bsum, bpre, NB);
    scan_add<<<NB, 256, 0, stream>>>(bpre, off, N, NB);
    scatter_kernel<<<(ET + 255) / 256, 256, 0, stream>>>(srcp, dstp, off, cur, perm, E, ET);

    // ---- GAT layer 1: fused softmax + aggregate + bias + relu (bf16 out) ----
    fused_gat4<<<(N + 3) / 4, 256, 0, stream>>>(off, perm, a_s, a_d, h1b, b1, out1b, N);

    // ---- GAT layer 2: MFMA GEMM + scores, then fused aggregate ----
    gemm2_mfma<<<(N + 63) / 64, 256, 0, stream>>>(out1b, w2t, as2, ad2, h2b, a_s, a_d, N);
    fused_gat1<<<(N + 3) / 4, 256, 0, stream>>>(off, perm, a_s, a_d, h2b, b2, out2, N);

    // ---- readout ----
    hipMemsetAsync(g, 0, 64 * sizeof(float), stream);
    colsum_kernel<<<512, 256, 0, stream>>>(out2, g, N);
    final_kernel<<<1, 64, 0, stream>>>(g, Wv, bv, out, N);
}